// Round 2
// baseline (2414.172 us; speedup 1.0000x reference)
//
#include <hip/hip_runtime.h>
#include <math.h>

#define DIMC 384
#define NHD 8
#define NSTATE 16
#define DINN 768
#define DTRK 24
#define BB 8
#define LSEQ 2304
#define MROWS (BB*LSEQ)   // 18432

__device__ __forceinline__ float sigmoid_(float x){ return 1.f/(1.f+__expf(-x)); }
__device__ __forceinline__ float silu_(float x){ return x*sigmoid_(x); }
__device__ __forceinline__ float softplus_(float x){ return (x>20.f)?x:log1pf(__expf(x)); }
__device__ __forceinline__ float gelu_(float x){
  float x3=x*x*x;
  return 0.5f*x*(1.f+tanhf(0.7978845608028654f*(x+0.044715f*x3)));
}
__device__ __forceinline__ float bfu2f(unsigned short u){
  union{unsigned int i; float f;} c; c.i=((unsigned int)u)<<16; return c.f;
}
__device__ __forceinline__ unsigned short f2bfu(float f){
  union{float f; unsigned int i;} c; c.f=f;
  unsigned int r = c.i + 0x7FFFu + ((c.i>>16)&1u);
  return (unsigned short)(r>>16);
}

// ---------------- transpose (B,C,L) -> (B,L,C) ----------------
__global__ void k_transpose(const float* __restrict__ x, float* __restrict__ xs){
  __shared__ float tile[32][33];
  int b = blockIdx.z;
  int t0 = blockIdx.x*32, c0 = blockIdx.y*32;
  int tx = threadIdx.x, ty = threadIdx.y; // 32 x 8
  const float* xb = x + (size_t)b*DIMC*LSEQ;
  #pragma unroll
  for(int q=0;q<4;q++)
    tile[ty+q*8][tx] = xb[(size_t)(c0+ty+q*8)*LSEQ + t0+tx];
  __syncthreads();
  float* xsb = xs + (size_t)b*LSEQ*DIMC;
  #pragma unroll
  for(int q=0;q<4;q++)
    xsb[(size_t)(t0+ty+q*8)*DIMC + c0+tx] = tile[tx][ty+q*8];
}

// -------- LN stats (mean/rstd per row) + attention scores (uses LN1 in regs) --------
__global__ __launch_bounds__(64) void k_lnstats_scores(const float* __restrict__ xs,
   const float* __restrict__ g1,const float* __restrict__ b1,
   const float* __restrict__ apw,const float* __restrict__ apb,
   float* __restrict__ meanr, float* __restrict__ rstdr, float* __restrict__ scores){
  int row = blockIdx.x;
  int lane = threadIdx.x;
  const float* xr = xs + (size_t)row*DIMC;
  float v[6];
  float s=0.f, s2=0.f;
  #pragma unroll
  for(int i=0;i<6;i++){ v[i]=xr[lane+i*64]; s+=v[i]; s2+=v[i]*v[i]; }
  #pragma unroll
  for(int m=32;m>=1;m>>=1){ s += __shfl_xor(s,m); s2 += __shfl_xor(s2,m); }
  float mean = s*(1.f/DIMC);
  float var  = s2*(1.f/DIMC)-mean*mean;
  float rstd = rsqrtf(var+1e-5f);
  if(lane==0){ meanr[row]=mean; rstdr[row]=rstd; }
  float xv1[6];
  #pragma unroll
  for(int i=0;i<6;i++){
    int c = lane+i*64;
    xv1[i] = (v[i]-mean)*rstd*g1[c]+b1[c];
  }
  #pragma unroll
  for(int h=0;h<NHD;h++){
    float p=0.f;
    #pragma unroll
    for(int i=0;i<6;i++) p += xv1[i]*apw[h*DIMC+lane+i*64];
    #pragma unroll
    for(int m=32;m>=1;m>>=1) p += __shfl_xor(p,m);
    if(lane==0) scores[(size_t)row*NHD+h]=p+apb[h];
  }
}

// ---------------- softmax over L per (b,h), in-place ----------------
__global__ __launch_bounds__(256) void k_softmax_L(float* __restrict__ sc){
  int bh = blockIdx.x; int b = bh>>3, h = bh&7;
  int tid = threadIdx.x;
  __shared__ float red[8];
  const size_t base = (size_t)b*LSEQ*NHD + h;
  float mx = -1e30f;
  for(int l=tid;l<LSEQ;l+=256) mx = fmaxf(mx, sc[base + (size_t)l*NHD]);
  #pragma unroll
  for(int m=32;m>=1;m>>=1) mx = fmaxf(mx, __shfl_xor(mx,m));
  if((tid&63)==0) red[tid>>6]=mx;
  __syncthreads();
  mx = fmaxf(fmaxf(red[0],red[1]),fmaxf(red[2],red[3]));
  float sum=0.f;
  for(int l=tid;l<LSEQ;l+=256) sum += __expf(sc[base+(size_t)l*NHD]-mx);
  #pragma unroll
  for(int m=32;m>=1;m>>=1) sum += __shfl_xor(sum,m);
  if((tid&63)==0) red[4+(tid>>6)]=sum;
  __syncthreads();
  float inv = 1.f/(red[4]+red[5]+red[6]+red[7]);
  for(int l=tid;l<LSEQ;l+=256){
    size_t idx = base+(size_t)l*NHD;
    sc[idx] = __expf(sc[idx]-mx)*inv;
  }
}

__global__ void k_wpool(const float* __restrict__ attn, float* __restrict__ w){
  int i = blockIdx.x*256+threadIdx.x;
  if(i<MROWS){
    const float* a = attn+(size_t)i*NHD;
    float s=0.f;
    #pragma unroll
    for(int h=0;h<NHD;h++) s+=a[h];
    w[i]=s*0.125f;
  }
}

__global__ void k_zero(float* __restrict__ p, int n){
  int i=blockIdx.x*256+threadIdx.x; if(i<n)p[i]=0.f;
}

// gc[b,c] = sum_l w[b,l]*xn1[b,l,c]  (xn1 recomputed from XS + mean/rstd)
__global__ __launch_bounds__(384) void k_gc(const float* __restrict__ w,
    const float* __restrict__ xs, const float* __restrict__ meanr,
    const float* __restrict__ rstdr, const float* __restrict__ g1,
    const float* __restrict__ b1, float* __restrict__ gc){
  int b = blockIdx.x; int chunk = blockIdx.y; int c = threadIdx.x;
  int l0 = chunk*192;
  float acc=0.f, accw=0.f;
  for(int l=0;l<192;l++){
    int row = b*LSEQ + l0+l;
    float ww = w[row];
    acc  += ww*(xs[(size_t)row*DIMC+c]-meanr[row])*rstdr[row];
    accw += ww;
  }
  atomicAdd(&gc[b*DIMC+c], acc*g1[c]+accw*b1[c]);
}

__global__ __launch_bounds__(64) void k_mod1(const float* __restrict__ gc,
    const float* __restrict__ w1, const float* __restrict__ b1, float* __restrict__ h){
  int b = blockIdx.x; int n = blockIdx.y*64+threadIdx.x;
  const float* g = gc + b*DIMC;
  const float* wr = w1 + (size_t)n*DIMC;
  float acc=0.f;
  for(int k=0;k<DIMC;k++) acc += g[k]*wr[k];
  h[b*768+n] = silu_(acc+b1[n]);
}
__global__ __launch_bounds__(64) void k_mod2(const float* __restrict__ h,
    const float* __restrict__ w2, const float* __restrict__ b2, float* __restrict__ mod){
  int b = blockIdx.x; int n = blockIdx.y*64+threadIdx.x;
  const float* hh = h + b*768;
  const float* wr = w2 + (size_t)n*768;
  float acc=0.f;
  for(int k=0;k<768;k++) acc += hh[k]*wr[k];
  mod[b*DIMC+n] = acc+b2[n];
}

// ---------------- tiled GEMM: out = epi(op(A) @ W^T + bias) ----------------
// A row-major (MROWS,K); W row-major (N,K). 64x64 tile, BK=16, 256 thr, 4x4/thr.
// ALN: A elements get LayerNorm (mean/rstd per row, g/b per col) applied on load.
// ABF16: A is bf16. OBF16: plain/gelu output stored as bf16.
// EPI: 0 plain, 1 gelu, 2 out += v*(1+aux[b,c]) in-place (out=XS),
//      3 final: out[(b*C+col)*L+t] = aux[row,col] + v  (residual + transpose)
template<int EPI, int ALN, int ABF16, int OBF16>
__global__ __launch_bounds__(256) void k_gemm(
    const void* __restrict__ Ap, const float* __restrict__ W,
    const float* __restrict__ bias, void* __restrict__ outp,
    int K, int N, const float* __restrict__ aux,
    const float* __restrict__ lnm, const float* __restrict__ lnr,
    const float* __restrict__ lng, const float* __restrict__ lnb)
{
  __shared__ float As[16][64];
  __shared__ float Ws[16][64];
  int tid = threadIdx.x;
  int tx = tid & 15, ty = tid >> 4;
  int m0 = blockIdx.x*64, n0 = blockIdx.y*64;
  int arow = tid >> 2, kq = (tid & 3) * 4;
  const bool nguard = (N & 63) != 0;
  float mu=0.f, rs=0.f;
  if(ALN){ mu = lnm[m0+arow]; rs = lnr[m0+arow]; }
  float acc[4][4] = {};
  for(int kb=0; kb<K; kb+=16){
    float4 av;
    if(ABF16){
      const unsigned short* A = (const unsigned short*)Ap;
      ushort4 u4 = *reinterpret_cast<const ushort4*>(&A[(size_t)(m0+arow)*K + kb + kq]);
      av.x=bfu2f(u4.x); av.y=bfu2f(u4.y); av.z=bfu2f(u4.z); av.w=bfu2f(u4.w);
    } else {
      const float* A = (const float*)Ap;
      av = *reinterpret_cast<const float4*>(&A[(size_t)(m0+arow)*K + kb + kq]);
    }
    if(ALN){
      float4 g4 = *reinterpret_cast<const float4*>(&lng[kb+kq]);
      float4 b4 = *reinterpret_cast<const float4*>(&lnb[kb+kq]);
      av.x=(av.x-mu)*rs*g4.x+b4.x;
      av.y=(av.y-mu)*rs*g4.y+b4.y;
      av.z=(av.z-mu)*rs*g4.z+b4.z;
      av.w=(av.w-mu)*rs*g4.w+b4.w;
    }
    float4 wv;
    if(!nguard || (n0+arow) < N)
      wv = *reinterpret_cast<const float4*>(&W[(size_t)(n0+arow)*K + kb + kq]);
    else wv = make_float4(0.f,0.f,0.f,0.f);
    __syncthreads();
    As[kq+0][arow]=av.x; As[kq+1][arow]=av.y; As[kq+2][arow]=av.z; As[kq+3][arow]=av.w;
    Ws[kq+0][arow]=wv.x; Ws[kq+1][arow]=wv.y; Ws[kq+2][arow]=wv.z; Ws[kq+3][arow]=wv.w;
    __syncthreads();
    #pragma unroll
    for(int k=0;k<16;k++){
      float4 a4 = *reinterpret_cast<const float4*>(&As[k][ty*4]);
      float4 w4 = *reinterpret_cast<const float4*>(&Ws[k][tx*4]);
      float aa[4]={a4.x,a4.y,a4.z,a4.w};
      float ww[4]={w4.x,w4.y,w4.z,w4.w};
      #pragma unroll
      for(int i=0;i<4;i++)
        #pragma unroll
        for(int j=0;j<4;j++)
          acc[i][j] += aa[i]*ww[j];
    }
  }
  #pragma unroll
  for(int i=0;i<4;i++){
    int row = m0 + ty*4 + i;
    #pragma unroll
    for(int j=0;j<4;j++){
      int col = n0 + tx*4 + j;
      if(nguard && col>=N) continue;
      float v = acc[i][j] + (bias ? bias[col] : 0.f);
      if(EPI==1) v = gelu_(v);
      if(EPI==0 || EPI==1){
        if(OBF16) ((unsigned short*)outp)[(size_t)row*N + col] = f2bfu(v);
        else      ((float*)outp)[(size_t)row*N + col] = v;
      } else if(EPI==2){
        int bi = row / LSEQ;
        ((float*)outp)[(size_t)row*DIMC + col] += v * (1.f + aux[bi*DIMC + col]);
      } else { // EPI==3
        int bi = row / LSEQ, t = row - bi*LSEQ;
        ((float*)outp)[((size_t)(bi*DIMC + col))*LSEQ + t] = aux[(size_t)row*DIMC + col] + v;
      }
    }
  }
}

// ---------------- causal depthwise conv K=4 + silu (f32 in, bf16 out) ----------------
__global__ void k_conv(const float* __restrict__ xm, const float* __restrict__ cw,
                       const float* __restrict__ cb, unsigned short* __restrict__ u){
  size_t i = (size_t)blockIdx.x*256+threadIdx.x;
  if(i >= (size_t)MROWS*DINN) return;
  int d = (int)(i % DINN);
  int r = (int)(i / DINN);
  int t = r % LSEQ;
  float acc = cb[d];
  #pragma unroll
  for(int k=0;k<4;k++){
    int tt = t + k - 3;
    if(tt>=0) acc += xm[(size_t)(r - t + tt)*DINN + d]*cw[d*4+k];
  }
  u[i] = f2bfu(silu_(acc));
}

// ---------------- small-K GEMM for delta (K=24) + softplus, bf16 out ----------------
__global__ __launch_bounds__(256) void k_dtgemm(const float* __restrict__ DBC,
    const float* __restrict__ dtw, const float* __restrict__ dtb,
    unsigned short* __restrict__ delta){
  __shared__ float As[64][24];
  __shared__ float Ws[64][24];
  int tid = threadIdx.x;
  int m0 = blockIdx.x*64, n0 = blockIdx.y*64;
  for(int j=tid;j<64*24;j+=256){
    int rr=j/24, kk=j-rr*24;
    As[rr][kk]=DBC[(size_t)(m0+rr)*56+kk];
    Ws[rr][kk]=dtw[(size_t)(n0+rr)*24+kk];
  }
  __syncthreads();
  int tx=tid&15, ty=tid>>4;
  float acc[4][4]={};
  for(int k=0;k<24;k++){
    float a[4],w[4];
    #pragma unroll
    for(int i=0;i<4;i++){a[i]=As[ty*4+i][k]; w[i]=Ws[tx*4+i][k];}
    #pragma unroll
    for(int i=0;i<4;i++)
      #pragma unroll
      for(int j=0;j<4;j++) acc[i][j]+=a[i]*w[j];
  }
  #pragma unroll
  for(int i=0;i<4;i++){
    int row=m0+ty*4+i;
    #pragma unroll
    for(int j=0;j<4;j++){
      int col=n0+tx*4+j;
      delta[(size_t)row*DINN+col]=f2bfu(softplus_(acc[i][j]+dtb[col]));
    }
  }
}

// ---------------- selective scan, fused (+u*Dp)*silu(z) epilogue ----------------
// dy holds delta (bf16) on entry, yact (bf16) on exit (in-place).
// 384 blocks: b in 0..7, dg in 0..47; 256 thr = 16 d x 16 n.
__global__ __launch_bounds__(256) void k_scan(
  unsigned short* dy,
  const unsigned short* __restrict__ u, const float* __restrict__ dbc,
  const unsigned short* __restrict__ z,
  const float* __restrict__ A_log, const float* __restrict__ Dp)
{
  int blk=blockIdx.x; int b=blk/48, dg=blk%48;
  int tid=threadIdx.x; int n=tid&15, dl=tid>>4;
  int d=dg*16+dl;
  float Ac = -__expf(A_log[d*NSTATE+n]);
  float Dv = Dp[d];
  float h=0.f;
  size_t rbase=(size_t)b*LSEQ;
  float dt_c=bfu2f(dy[rbase*DINN+d]), uv_c=bfu2f(u[rbase*DINN+d]);
  float Bv_c=dbc[rbase*56+DTRK+n], Cv_c=dbc[rbase*56+DTRK+NSTATE+n];
  float zv_c=bfu2f(z[rbase*DINN+d]);
  for(int t=0;t<LSEQ;t++){
    float dt_n=0.f,uv_n=0.f,Bv_n=0.f,Cv_n=0.f,zv_n=0.f;
    if(t+1<LSEQ){
      size_t r=rbase+t+1;
      dt_n=bfu2f(dy[r*DINN+d]); uv_n=bfu2f(u[r*DINN+d]);
      Bv_n=dbc[r*56+DTRK+n]; Cv_n=dbc[r*56+DTRK+NSTATE+n];
      zv_n=bfu2f(z[r*DINN+d]);
    }
    float dA=__expf(dt_c*Ac);
    h = h*dA + dt_c*uv_c*Bv_c;
    float p = h*Cv_c;
    p+=__shfl_xor(p,8); p+=__shfl_xor(p,4); p+=__shfl_xor(p,2); p+=__shfl_xor(p,1);
    if(n==0){
      float yv=(p + uv_c*Dv)*silu_(zv_c);
      dy[(rbase+t)*DINN+d]=f2bfu(yv);
    }
    dt_c=dt_n;uv_c=uv_n;Bv_c=Bv_n;Cv_c=Cv_n;zv_c=zv_n;
  }
}

// ---------------- single LN (n3), f32 out ----------------
__global__ __launch_bounds__(64) void k_ln(const float* __restrict__ xin,
    const float* __restrict__ g, const float* __restrict__ bb, float* __restrict__ xout){
  int row = blockIdx.x;
  int lane = threadIdx.x;
  const float* xr = xin + (size_t)row*DIMC;
  float v[6];
  float s=0.f, s2=0.f;
  #pragma unroll
  for(int i=0;i<6;i++){ v[i]=xr[lane+i*64]; s+=v[i]; s2+=v[i]*v[i]; }
  #pragma unroll
  for(int m=32;m>=1;m>>=1){ s += __shfl_xor(s,m); s2 += __shfl_xor(s2,m); }
  float mean = s*(1.f/DIMC);
  float var  = s2*(1.f/DIMC)-mean*mean;
  float rstd = rsqrtf(var+1e-5f);
  #pragma unroll
  for(int i=0;i<6;i++){
    int c = lane+i*64;
    xout[(size_t)row*DIMC+c] = (v[i]-mean)*rstd*g[c]+bb[c];
  }
}

extern "C" void kernel_launch(void* const* d_in, const int* in_sizes, int n_in,
                              void* d_out, int out_size, void* d_ws, size_t ws_size,
                              hipStream_t stream)
{
  const float* x     = (const float*)d_in[0];
  const float* n1g   = (const float*)d_in[1];
  const float* n1b   = (const float*)d_in[2];
  const float* apw   = (const float*)d_in[3];
  const float* apb   = (const float*)d_in[4];
  const float* n2g   = (const float*)d_in[5];
  const float* n2b   = (const float*)d_in[6];
  const float* inw   = (const float*)d_in[7];
  const float* inb   = (const float*)d_in[8];
  const float* convw = (const float*)d_in[9];
  const float* convb = (const float*)d_in[10];
  const float* xpw   = (const float*)d_in[11];
  const float* dtw   = (const float*)d_in[12];
  const float* dtb   = (const float*)d_in[13];
  const float* Alog  = (const float*)d_in[14];
  const float* Dp    = (const float*)d_in[15];
  const float* outw  = (const float*)d_in[16];
  const float* outb  = (const float*)d_in[17];
  const float* modw1 = (const float*)d_in[18];
  const float* modb1 = (const float*)d_in[19];
  const float* modw2 = (const float*)d_in[20];
  const float* modb2 = (const float*)d_in[21];
  const float* n3g   = (const float*)d_in[22];
  const float* n3b   = (const float*)d_in[23];
  const float* fc1w  = (const float*)d_in[24];
  const float* fc1b  = (const float*)d_in[25];
  const float* fc2w  = (const float*)d_in[26];
  const float* fc2b  = (const float*)d_in[27];

  // ---- workspace layout (floats), total ~29.56M floats = 118 MB ----
  float* ws = (float*)d_ws;
  size_t off = 0;
  float* XS    = ws + off; off += (size_t)MROWS*DIMC;          // 7,077,888
  float* BIG   = ws + off; off += (size_t)21233664;            // 81 MB region
  //   BIG usage over time:
  //   [0 .. 14.16M f)  : XM f32 (in_proj xm)  -> then DELTAb bf16 (7.08M f) -> then F1b bf16 (14.16M f)
  //   [14.16M .. 21.2M): Zb bf16 (7.08M f slots)
  float*          XM     = BIG;
  unsigned short* DELTAb = (unsigned short*)BIG;
  unsigned short* F1b    = (unsigned short*)BIG;
  unsigned short* Zb     = (unsigned short*)(BIG + 14155776);
  float* DBC   = ws + off; off += (size_t)MROWS*56;            // 1,032,192
  float* SCORES= ws + off; off += (size_t)MROWS*NHD;           // 147,456
  float* WPOOL = ws + off; off += MROWS;
  float* MEANR = ws + off; off += MROWS;
  float* RSTDR = ws + off; off += MROWS;
  float* GC    = ws + off; off += BB*DIMC;
  float* MODH  = ws + off; off += BB*768;
  float* MOD   = ws + off; off += BB*DIMC;
  (void)ws_size; (void)n_in; (void)in_sizes; (void)out_size;

  // d_out doubles as scratch: u (bf16, 28,311,552 B == out bytes), later H (f32 LN3 out).
  unsigned short* Ub = (unsigned short*)d_out;
  float*          Hf = (float*)d_out;

  k_transpose<<<dim3(72,12,8), dim3(32,8), 0, stream>>>(x, XS);
  k_lnstats_scores<<<MROWS, 64, 0, stream>>>(XS, n1g,n1b, apw,apb, MEANR, RSTDR, SCORES);
  k_softmax_L<<<BB*NHD, 256, 0, stream>>>(SCORES);
  k_wpool<<<(MROWS+255)/256, 256, 0, stream>>>(SCORES, WPOOL);
  k_zero<<<(BB*DIMC+255)/256, 256, 0, stream>>>(GC, BB*DIMC);
  k_gc<<<dim3(BB,12), 384, 0, stream>>>(WPOOL, XS, MEANR, RSTDR, n1g, n1b, GC);
  k_mod1<<<dim3(BB,12), 64, 0, stream>>>(GC, modw1, modb1, MODH);
  k_mod2<<<dim3(BB,6), 64, 0, stream>>>(MODH, modw2, modb2, MOD);
  // in_proj xm half: XM = LN2(XS) @ inw[0:768]^T + inb[0:768]   (f32 out)
  k_gemm<0,1,0,0><<<dim3(288,12), 256, 0, stream>>>(XS, inw, inb, XM,
      384, 768, nullptr, MEANR, RSTDR, n2g, n2b);
  // in_proj z half: Zb = LN2(XS) @ inw[768:]^T + inb[768:]      (bf16 out)
  k_gemm<0,1,0,1><<<dim3(288,12), 256, 0, stream>>>(XS, inw+(size_t)768*384, inb+768, Zb,
      384, 768, nullptr, MEANR, RSTDR, n2g, n2b);
  // conv + silu -> Ub (bf16, in d_out)
  k_conv<<<(int)(((size_t)MROWS*DINN+255)/256), 256, 0, stream>>>(XM, convw, convb, Ub);
  // dbc = u @ xp_w^T   (A bf16, K=768, N=56)
  k_gemm<0,0,1,0><<<dim3(288,1), 256, 0, stream>>>(Ub, xpw, nullptr, DBC,
      768, 56, nullptr, nullptr,nullptr,nullptr,nullptr);
  // delta = softplus(dbc[:, :24] @ dt_w^T + dt_b) -> DELTAb (bf16, overwrites XM)
  k_dtgemm<<<dim3(288,12), 256, 0, stream>>>(DBC, dtw, dtb, DELTAb);
  // selective scan: yact (bf16) in-place into DELTAb
  k_scan<<<384, 256, 0, stream>>>(DELTAb, Ub, DBC, Zb, Alog, Dp);
  // XS += (yact @ out_w^T + out_b) * (1 + mod)   (A bf16, K=768, N=384)
  k_gemm<2,0,1,0><<<dim3(288,6), 256, 0, stream>>>(DELTAb, outw, outb, XS,
      768, 384, MOD, nullptr,nullptr,nullptr,nullptr);
  // H = LN3(XS) -> d_out scratch (f32)
  k_ln<<<MROWS, 64, 0, stream>>>(XS, n3g, n3b, Hf);
  // F1b = gelu(H @ fc1_w^T + fc1_b)   (bf16 out, overwrites DELTAb/Zb region)
  k_gemm<1,0,0,1><<<dim3(288,24), 256, 0, stream>>>(Hf, fc1w, fc1b, F1b,
      384, 1536, nullptr, nullptr,nullptr,nullptr,nullptr);
  // d_out = transpose(XS + F1 @ fc2_w^T + fc2_b)   (A bf16, K=1536, N=384)
  k_gemm<3,0,1,0><<<dim3(288,6), 256, 0, stream>>>(F1b, fc2w, fc2b, d_out,
      1536, 384, XS, nullptr,nullptr,nullptr,nullptr);
}

// Round 3
// 854.830 us; speedup vs baseline: 2.8242x; 2.8242x over previous
//
#include <hip/hip_runtime.h>
#include <math.h>

#define DIMC 384
#define NHD 8
#define NSTATE 16
#define DINN 768
#define DTRK 24
#define BB 8
#define LSEQ 2304
#define MROWS (BB*LSEQ)   // 18432
#define NCH 16
#define TCH 144           // LSEQ / NCH

typedef unsigned short u16;
typedef short bf16x8 __attribute__((ext_vector_type(8)));
typedef float f32x4 __attribute__((ext_vector_type(4)));

__device__ __forceinline__ float sigmoid_(float x){ return 1.f/(1.f+__expf(-x)); }
__device__ __forceinline__ float silu_(float x){ return x*sigmoid_(x); }
__device__ __forceinline__ float softplus_(float x){ return (x>20.f)?x:log1pf(__expf(x)); }
__device__ __forceinline__ float gelu_(float x){
  float x3=x*x*x;
  return 0.5f*x*(1.f+tanhf(0.7978845608028654f*(x+0.044715f*x3)));
}
__device__ __forceinline__ float bfu2f(u16 u){
  union{unsigned int i; float f;} c; c.i=((unsigned int)u)<<16; return c.f;
}
__device__ __forceinline__ u16 f2bfu(float f){
  union{float f; unsigned int i;} c; c.f=f;
  unsigned int r = c.i + 0x7FFFu + ((c.i>>16)&1u);
  return (u16)(r>>16);
}

// ---------------- weight f32 -> bf16 convert ----------------
__global__ void k_cvt(const float* __restrict__ s, u16* __restrict__ d, int n){
  int i=blockIdx.x*256+threadIdx.x; if(i<n) d[i]=f2bfu(s[i]);
}
__global__ void k_cvtpad(const float* __restrict__ s, u16* __restrict__ d, int nsrc, int ntot){
  int i=blockIdx.x*256+threadIdx.x; if(i<ntot) d[i] = (i<nsrc)? f2bfu(s[i]) : (u16)0;
}

// ---------------- transpose (B,C,L) -> (B,L,C) ----------------
__global__ void k_transpose(const float* __restrict__ x, float* __restrict__ xs){
  __shared__ float tile[32][33];
  int b = blockIdx.z;
  int t0 = blockIdx.x*32, c0 = blockIdx.y*32;
  int tx = threadIdx.x, ty = threadIdx.y; // 32 x 8
  const float* xb = x + (size_t)b*DIMC*LSEQ;
  #pragma unroll
  for(int q=0;q<4;q++)
    tile[ty+q*8][tx] = xb[(size_t)(c0+ty+q*8)*LSEQ + t0+tx];
  __syncthreads();
  float* xsb = xs + (size_t)b*LSEQ*DIMC;
  #pragma unroll
  for(int q=0;q<4;q++)
    xsb[(size_t)(t0+ty+q*8)*DIMC + c0+tx] = tile[tx][ty+q*8];
}

// -------- LN stats + LN2 (bf16 out) + attention scores --------
__global__ __launch_bounds__(64) void k_lnstats(const float* __restrict__ xs,
   const float* __restrict__ g1,const float* __restrict__ b1,
   const float* __restrict__ g2,const float* __restrict__ b2,
   const float* __restrict__ apw,const float* __restrict__ apb,
   float* __restrict__ meanr, float* __restrict__ rstdr,
   u16* __restrict__ xn2, float* __restrict__ scores){
  int row = blockIdx.x;
  int lane = threadIdx.x;
  const float* xr = xs + (size_t)row*DIMC;
  float v[6];
  float s=0.f, s2=0.f;
  #pragma unroll
  for(int i=0;i<6;i++){ v[i]=xr[lane+i*64]; s+=v[i]; s2+=v[i]*v[i]; }
  #pragma unroll
  for(int m=32;m>=1;m>>=1){ s += __shfl_xor(s,m); s2 += __shfl_xor(s2,m); }
  float mean = s*(1.f/DIMC);
  float var  = s2*(1.f/DIMC)-mean*mean;
  float rstd = rsqrtf(var+1e-5f);
  if(lane==0){ meanr[row]=mean; rstdr[row]=rstd; }
  float xv1[6];
  #pragma unroll
  for(int i=0;i<6;i++){
    int c = lane+i*64;
    float nx = (v[i]-mean)*rstd;
    xv1[i] = nx*g1[c]+b1[c];
    xn2[(size_t)row*DIMC+c] = f2bfu(nx*g2[c]+b2[c]);
  }
  #pragma unroll
  for(int h=0;h<NHD;h++){
    float p=0.f;
    #pragma unroll
    for(int i=0;i<6;i++) p += xv1[i]*apw[h*DIMC+lane+i*64];
    #pragma unroll
    for(int m=32;m>=1;m>>=1) p += __shfl_xor(p,m);
    if(lane==0) scores[(size_t)row*NHD+h]=p+apb[h];
  }
}

// ---------------- softmax over L per (b,h), in-place ----------------
__global__ __launch_bounds__(256) void k_softmax_L(float* __restrict__ sc){
  int bh = blockIdx.x; int b = bh>>3, h = bh&7;
  int tid = threadIdx.x;
  __shared__ float red[8];
  const size_t base = (size_t)b*LSEQ*NHD + h;
  float mx = -1e30f;
  for(int l=tid;l<LSEQ;l+=256) mx = fmaxf(mx, sc[base + (size_t)l*NHD]);
  #pragma unroll
  for(int m=32;m>=1;m>>=1) mx = fmaxf(mx, __shfl_xor(mx,m));
  if((tid&63)==0) red[tid>>6]=mx;
  __syncthreads();
  mx = fmaxf(fmaxf(red[0],red[1]),fmaxf(red[2],red[3]));
  float sum=0.f;
  for(int l=tid;l<LSEQ;l+=256) sum += __expf(sc[base+(size_t)l*NHD]-mx);
  #pragma unroll
  for(int m=32;m>=1;m>>=1) sum += __shfl_xor(sum,m);
  if((tid&63)==0) red[4+(tid>>6)]=sum;
  __syncthreads();
  float inv = 1.f/(red[4]+red[5]+red[6]+red[7]);
  for(int l=tid;l<LSEQ;l+=256){
    size_t idx = base+(size_t)l*NHD;
    sc[idx] = __expf(sc[idx]-mx)*inv;
  }
}

__global__ void k_wpool(const float* __restrict__ attn, float* __restrict__ w){
  int i = blockIdx.x*256+threadIdx.x;
  if(i<MROWS){
    const float* a = attn+(size_t)i*NHD;
    float s=0.f;
    #pragma unroll
    for(int h=0;h<NHD;h++) s+=a[h];
    w[i]=s*0.125f;
  }
}

__global__ void k_zero(float* __restrict__ p, int n){
  int i=blockIdx.x*256+threadIdx.x; if(i<n)p[i]=0.f;
}

// gc[b,c] = sum_l w[b,l]*xn1[b,l,c]  (xn1 recomputed from XS + mean/rstd)
__global__ __launch_bounds__(384) void k_gc(const float* __restrict__ w,
    const float* __restrict__ xs, const float* __restrict__ meanr,
    const float* __restrict__ rstdr, const float* __restrict__ g1,
    const float* __restrict__ b1, float* __restrict__ gc){
  int b = blockIdx.x; int chunk = blockIdx.y; int c = threadIdx.x;
  int l0 = chunk*192;
  float acc=0.f, accw=0.f;
  for(int l=0;l<192;l++){
    int row = b*LSEQ + l0+l;
    float ww = w[row];
    acc  += ww*(xs[(size_t)row*DIMC+c]-meanr[row])*rstdr[row];
    accw += ww;
  }
  atomicAdd(&gc[b*DIMC+c], acc*g1[c]+accw*b1[c]);
}

__global__ __launch_bounds__(64) void k_mod1(const float* __restrict__ gc,
    const float* __restrict__ w1, const float* __restrict__ b1, float* __restrict__ h){
  int b = blockIdx.x; int n = blockIdx.y*64+threadIdx.x;
  const float* g = gc + b*DIMC;
  const float* wr = w1 + (size_t)n*DIMC;
  float acc=0.f;
  for(int k=0;k<DIMC;k++) acc += g[k]*wr[k];
  h[b*768+n] = silu_(acc+b1[n]);
}
__global__ __launch_bounds__(64) void k_mod2(const float* __restrict__ h,
    const float* __restrict__ w2, const float* __restrict__ b2, float* __restrict__ mod){
  int b = blockIdx.x; int n = blockIdx.y*64+threadIdx.x;
  const float* hh = h + b*768;
  const float* wr = w2 + (size_t)n*768;
  float acc=0.f;
  for(int k=0;k<768;k++) acc += hh[k]*wr[k];
  mod[b*DIMC+n] = acc+b2[n];
}

// =====================  bf16 MFMA GEMM  =====================
// out = epi(A @ W^T + bias).  A:(M,K) bf16 row-major, W:(N,K) bf16 row-major.
// Tile 128x128, BK=32, 256 threads = 4 waves (2x2 of 64x64).
// mfma_f32_16x16x32_bf16: a-frag lane l = A[m=l&15][k=(l>>4)*8+i];
// b-frag lane l = W[n=l&15][k=(l>>4)*8+i]; D lane l reg r = [m=(l>>4)*4+r][n=l&15].
// EPI: 0 bf16 store, 1 gelu->bf16, 2 f32: out += v*(1+aux[b,col]) in place,
//      3 final: d_out[(b*C+col)*L+t] = aux[row,col]+v (float4), 4 f32 store col<N guard.
template<int EPI>
__global__ __launch_bounds__(256,2) void k_mgemm(
    const u16* __restrict__ A, const u16* __restrict__ W,
    const float* __restrict__ bias, void* __restrict__ outp,
    int K, int N, const float* __restrict__ aux)
{
  __shared__ u16 lA[4096];   // [kc:4][row:128][8]
  __shared__ u16 lB[4096];
  int tid = threadIdx.x;
  int m0 = blockIdx.x*128, n0 = blockIdx.y*128;
  int wid = tid>>6, lane = tid&63;
  int wr = wid>>1, wc = wid&1;
  int lrow = lane&15, lk = lane>>4;
  f32x4 acc[4][4];
  #pragma unroll
  for(int i=0;i<4;i++)
    #pragma unroll
    for(int j=0;j<4;j++){ acc[i][j][0]=0.f; acc[i][j][1]=0.f; acc[i][j][2]=0.f; acc[i][j][3]=0.f; }

  int srow = tid>>2, skc = tid&3;
  const u16* Aptr = A + (size_t)(m0+srow)*K + skc*8;
  const u16* Wptr = W + (size_t)(n0+srow)*K + skc*8;
  u16* lAp = &lA[(skc*128 + srow)*8];
  u16* lBp = &lB[(skc*128 + srow)*8];

  for(int kb=0; kb<K; kb+=32){
    uint4 a0 = *reinterpret_cast<const uint4*>(Aptr + kb);
    uint4 a1 = *reinterpret_cast<const uint4*>(Aptr + (size_t)64*K + kb);
    uint4 b0 = *reinterpret_cast<const uint4*>(Wptr + kb);
    uint4 b1 = *reinterpret_cast<const uint4*>(Wptr + (size_t)64*K + kb);
    __syncthreads();
    *reinterpret_cast<uint4*>(lAp)       = a0;
    *reinterpret_cast<uint4*>(lAp + 512) = a1;
    *reinterpret_cast<uint4*>(lBp)       = b0;
    *reinterpret_cast<uint4*>(lBp + 512) = b1;
    __syncthreads();
    bf16x8 af[4], bf[4];
    #pragma unroll
    for(int i=0;i<4;i++){
      af[i] = *reinterpret_cast<const bf16x8*>(&lA[(lk*128 + wr*64 + i*16 + lrow)*8]);
      bf[i] = *reinterpret_cast<const bf16x8*>(&lB[(lk*128 + wc*64 + i*16 + lrow)*8]);
    }
    #pragma unroll
    for(int i=0;i<4;i++)
      #pragma unroll
      for(int j=0;j<4;j++)
        acc[i][j] = __builtin_amdgcn_mfma_f32_16x16x32_bf16(af[i], bf[j], acc[i][j], 0,0,0);
  }

  #pragma unroll
  for(int i=0;i<4;i++){
    int row = m0 + wr*64 + i*16 + lk*4;
    #pragma unroll
    for(int j=0;j<4;j++){
      int col = n0 + wc*64 + j*16 + lrow;
      float bc = bias ? bias[col] : 0.f;
      f32x4 v = acc[i][j];
      if(EPI==0){
        u16* o = (u16*)outp;
        #pragma unroll
        for(int r=0;r<4;r++) o[(size_t)(row+r)*N + col] = f2bfu(v[r]+bc);
      } else if(EPI==1){
        u16* o = (u16*)outp;
        #pragma unroll
        for(int r=0;r<4;r++) o[(size_t)(row+r)*N + col] = f2bfu(gelu_(v[r]+bc));
      } else if(EPI==2){
        float* o = (float*)outp;
        int bi = row/LSEQ;
        float sc = 1.f + aux[bi*DIMC + col];
        #pragma unroll
        for(int r=0;r<4;r++) o[(size_t)(row+r)*DIMC + col] += (v[r]+bc)*sc;
      } else if(EPI==3){
        float* o = (float*)outp;
        int bi = row/LSEQ, t = row - bi*LSEQ;
        float4 s;
        s.x = aux[(size_t)(row+0)*DIMC+col] + v[0] + bc;
        s.y = aux[(size_t)(row+1)*DIMC+col] + v[1] + bc;
        s.z = aux[(size_t)(row+2)*DIMC+col] + v[2] + bc;
        s.w = aux[(size_t)(row+3)*DIMC+col] + v[3] + bc;
        *reinterpret_cast<float4*>(&o[((size_t)(bi*DIMC+col))*LSEQ + t]) = s;
      } else { // EPI==4
        float* o = (float*)outp;
        if(col < N){
          #pragma unroll
          for(int r=0;r<4;r++) o[(size_t)(row+r)*N + col] = v[r]+bc;
        }
      }
    }
  }
}

// ---------------- causal depthwise conv K=4 + silu (bf16 in, bf16 out) ----------------
__global__ void k_conv(const u16* __restrict__ xm, const float* __restrict__ cw,
                       const float* __restrict__ cb, u16* __restrict__ u){
  size_t i = (size_t)blockIdx.x*256+threadIdx.x;
  if(i >= (size_t)MROWS*DINN) return;
  int d = (int)(i % DINN);
  int r = (int)(i / DINN);
  int t = r % LSEQ;
  float acc = cb[d];
  #pragma unroll
  for(int k=0;k<4;k++){
    int tt = t + k - 3;
    if(tt>=0) acc += bfu2f(xm[(size_t)(r - t + tt)*DINN + d])*cw[d*4+k];
  }
  u[i] = f2bfu(silu_(acc));
}

// ---------------- small-K GEMM for delta (K=24) + softplus, bf16 out ----------------
__global__ __launch_bounds__(256) void k_dtgemm(const float* __restrict__ DBC,
    const float* __restrict__ dtw, const float* __restrict__ dtb,
    u16* __restrict__ delta){
  __shared__ float As[64][24];
  __shared__ float Ws[64][24];
  int tid = threadIdx.x;
  int m0 = blockIdx.x*64, n0 = blockIdx.y*64;
  for(int j=tid;j<64*24;j+=256){
    int rr=j/24, kk=j-rr*24;
    As[rr][kk]=DBC[(size_t)(m0+rr)*56+kk];
    Ws[rr][kk]=dtw[(size_t)(n0+rr)*24+kk];
  }
  __syncthreads();
  int tx=tid&15, ty=tid>>4;
  float acc[4][4]={};
  for(int k=0;k<24;k++){
    float a[4],w[4];
    #pragma unroll
    for(int i=0;i<4;i++){a[i]=As[ty*4+i][k]; w[i]=Ws[tx*4+i][k];}
    #pragma unroll
    for(int i=0;i<4;i++)
      #pragma unroll
      for(int j=0;j<4;j++) acc[i][j]+=a[i]*w[j];
  }
  #pragma unroll
  for(int i=0;i<4;i++){
    int row=m0+ty*4+i;
    #pragma unroll
    for(int j=0;j<4;j++){
      int col=n0+tx*4+j;
      delta[(size_t)row*DINN+col]=f2bfu(softplus_(acc[i][j]+dtb[col]));
    }
  }
}

// ============ chunked selective scan ============
// pass 1: per (b,chunk,d,n) compute local (prod dA, h_local) with h=0
__global__ __launch_bounds__(256) void k_scan1(
  const u16* __restrict__ delta, const u16* __restrict__ u,
  const float* __restrict__ dbc, const float* __restrict__ A_log,
  float* __restrict__ aprod, float* __restrict__ hloc)
{
  int blk=blockIdx.x;
  int ch = blk & (NCH-1); int rest = blk>>4;
  int dg = rest%48; int b = rest/48;
  int tid=threadIdx.x; int n=tid&15, dl=tid>>4;
  int d=dg*16+dl;
  float Ac = -__expf(A_log[d*NSTATE+n]);
  float h=0.f, ap=1.f;
  size_t rbase=(size_t)b*LSEQ + (size_t)ch*TCH;
  float dt_c=bfu2f(delta[rbase*DINN+d]), uv_c=bfu2f(u[rbase*DINN+d]);
  float Bv_c=dbc[rbase*56+DTRK+n];
  for(int t=0;t<TCH;t++){
    float dt_n=0.f,uv_n=0.f,Bv_n=0.f;
    if(t+1<TCH){
      size_t r=rbase+t+1;
      dt_n=bfu2f(delta[r*DINN+d]); uv_n=bfu2f(u[r*DINN+d]); Bv_n=dbc[r*56+DTRK+n];
    }
    float dA=__expf(dt_c*Ac);
    h = h*dA + dt_c*uv_c*Bv_c;
    ap *= dA;
    dt_c=dt_n;uv_c=uv_n;Bv_c=Bv_n;
  }
  size_t idx = (((size_t)b*NCH+ch)*DINN + d)*NSTATE + n;
  aprod[idx]=ap; hloc[idx]=h;
}

// pass 2: sequential combine over chunks; hloc becomes h_in per chunk
__global__ __launch_bounds__(256) void k_scan2(
  const float* __restrict__ aprod, float* __restrict__ hl)
{
  int gid = blockIdx.x*256+threadIdx.x;   // 98304 = 8*768*16
  int n = gid & 15; int d = (gid>>4)%DINN; int b = gid/(DINN*NSTATE);
  float hin=0.f;
  for(int ch=0; ch<NCH; ch++){
    size_t idx = (((size_t)b*NCH+ch)*DINN + d)*NSTATE + n;
    float a = aprod[idx], h = hl[idx];
    hl[idx] = hin;
    hin = a*hin + h;
  }
}

// pass 3: re-run each chunk with correct h_in; write y (+u*Dp)*silu(z) into delta (in place)
__global__ __launch_bounds__(256) void k_scan3(
  u16* dy, const u16* __restrict__ u, const float* __restrict__ dbc,
  const u16* __restrict__ z, const float* __restrict__ A_log,
  const float* __restrict__ Dp, const float* __restrict__ hin)
{
  int blk=blockIdx.x;
  int ch = blk & (NCH-1); int rest = blk>>4;
  int dg = rest%48; int b = rest/48;
  int tid=threadIdx.x; int n=tid&15, dl=tid>>4;
  int d=dg*16+dl;
  float Ac = -__expf(A_log[d*NSTATE+n]);
  float Dv = Dp[d];
  size_t hidx = (((size_t)b*NCH+ch)*DINN + d)*NSTATE + n;
  float h = hin[hidx];
  size_t rbase=(size_t)b*LSEQ + (size_t)ch*TCH;
  float dt_c=bfu2f(dy[rbase*DINN+d]), uv_c=bfu2f(u[rbase*DINN+d]);
  float Bv_c=dbc[rbase*56+DTRK+n], Cv_c=dbc[rbase*56+DTRK+NSTATE+n];
  float zv_c=bfu2f(z[rbase*DINN+d]);
  for(int t=0;t<TCH;t++){
    float dt_n=0.f,uv_n=0.f,Bv_n=0.f,Cv_n=0.f,zv_n=0.f;
    if(t+1<TCH){
      size_t r=rbase+t+1;
      dt_n=bfu2f(dy[r*DINN+d]); uv_n=bfu2f(u[r*DINN+d]);
      Bv_n=dbc[r*56+DTRK+n]; Cv_n=dbc[r*56+DTRK+NSTATE+n];
      zv_n=bfu2f(z[r*DINN+d]);
    }
    float dA=__expf(dt_c*Ac);
    h = h*dA + dt_c*uv_c*Bv_c;
    float p = h*Cv_c;
    p+=__shfl_xor(p,8); p+=__shfl_xor(p,4); p+=__shfl_xor(p,2); p+=__shfl_xor(p,1);
    if(n==0){
      float yv=(p + uv_c*Dv)*silu_(zv_c);
      dy[(rbase+t)*DINN+d]=f2bfu(yv);
    }
    dt_c=dt_n;uv_c=uv_n;Bv_c=Bv_n;Cv_c=Cv_n;zv_c=zv_n;
  }
}

// ---------------- LN3, bf16 out ----------------
__global__ __launch_bounds__(64) void k_ln3(const float* __restrict__ xin,
    const float* __restrict__ g, const float* __restrict__ bb, u16* __restrict__ xout){
  int row = blockIdx.x;
  int lane = threadIdx.x;
  const float* xr = xin + (size_t)row*DIMC;
  float v[6];
  float s=0.f, s2=0.f;
  #pragma unroll
  for(int i=0;i<6;i++){ v[i]=xr[lane+i*64]; s+=v[i]; s2+=v[i]*v[i]; }
  #pragma unroll
  for(int m=32;m>=1;m>>=1){ s += __shfl_xor(s,m); s2 += __shfl_xor(s2,m); }
  float mean = s*(1.f/DIMC);
  float var  = s2*(1.f/DIMC)-mean*mean;
  float rstd = rsqrtf(var+1e-5f);
  #pragma unroll
  for(int i=0;i<6;i++){
    int c = lane+i*64;
    xout[(size_t)row*DIMC+c] = f2bfu((v[i]-mean)*rstd*g[c]+bb[c]);
  }
}

extern "C" void kernel_launch(void* const* d_in, const int* in_sizes, int n_in,
                              void* d_out, int out_size, void* d_ws, size_t ws_size,
                              hipStream_t stream)
{
  const float* x     = (const float*)d_in[0];
  const float* n1g   = (const float*)d_in[1];
  const float* n1b   = (const float*)d_in[2];
  const float* apw   = (const float*)d_in[3];
  const float* apb   = (const float*)d_in[4];
  const float* n2g   = (const float*)d_in[5];
  const float* n2b   = (const float*)d_in[6];
  const float* inw   = (const float*)d_in[7];
  const float* inb   = (const float*)d_in[8];
  const float* convw = (const float*)d_in[9];
  const float* convb = (const float*)d_in[10];
  const float* xpw   = (const float*)d_in[11];
  const float* dtw   = (const float*)d_in[12];
  const float* dtb   = (const float*)d_in[13];
  const float* Alog  = (const float*)d_in[14];
  const float* Dp    = (const float*)d_in[15];
  const float* outw  = (const float*)d_in[16];
  const float* outb  = (const float*)d_in[17];
  const float* modw1 = (const float*)d_in[18];
  const float* modb1 = (const float*)d_in[19];
  const float* modw2 = (const float*)d_in[20];
  const float* modb2 = (const float*)d_in[21];
  const float* n3g   = (const float*)d_in[22];
  const float* n3b   = (const float*)d_in[23];
  const float* fc1w  = (const float*)d_in[24];
  const float* fc1b  = (const float*)d_in[25];
  const float* fc2w  = (const float*)d_in[26];
  const float* fc2b  = (const float*)d_in[27];

  // ---- workspace layout (f32 slots), total 30,640,128 f = 122.6 MB ----
  float* ws = (float*)d_ws;
  float* XS    = ws;                       // 7,077,888 f
  float* BIG   = ws + 7077888;             // 14,155,776 f multi-use region
  u16*   XMb   = (u16*)BIG;                      // phase A: xm bf16 (18432x768)
  u16*   Zb    = (u16*)BIG + 14155776;           // phase A..scan: z bf16
  float* APROD = BIG;                            // phase B: 1,572,864 f
  float* HL    = BIG + 1572864;                  // phase B: 1,572,864 f
  u16*   F1b   = (u16*)BIG;                      // phase C: fc1 out bf16 (18432x1536)
  u16*   DELTAb= (u16*)(ws + 21233664);    // 7,077,888 f slots (delta/yact bf16)
  float* DBC   = ws + 28311552;            // 1,032,192 f
  float* WB    = ws + 29343744;            // bf16 weights, 1,081,344 f slots
  u16*   inw_b   = (u16*)WB;                     // 589,824 sh
  u16*   xpw_pad = inw_b + 589824;               // 98,304 sh (128x768, zero pad rows 56+)
  u16*   outw_b  = xpw_pad + 98304;              // 294,912 sh
  u16*   fc1w_b  = outw_b + 294912;              // 589,824 sh
  u16*   fc2w_b  = fc1w_b + 589824;              // 589,824 sh
  float* SCORES= ws + 30425088;            // 147,456 f
  float* WPOOL = ws + 30572544;            // 18,432
  float* MEANR = ws + 30590976;            // 18,432
  float* RSTDR = ws + 30609408;            // 18,432
  float* GC    = ws + 30627840;            // 3,072
  float* MODH  = ws + 30630912;            // 6,144
  float* MOD   = ws + 30637056;            // 3,072
  (void)ws_size; (void)n_in; (void)in_sizes; (void)out_size;

  // d_out as scratch: XN2b bf16 [0,14.2MB) -> Ub bf16 [0,28.3MB) -> Hb bf16 [0,14.2MB)
  u16* XN2b = (u16*)d_out;
  u16* Ub   = (u16*)d_out;
  u16* Hb   = (u16*)d_out;

  // weight conversion
  k_cvt<<<(589824+255)/256, 256, 0, stream>>>(inw,  inw_b,  589824);
  k_cvtpad<<<(98304+255)/256, 256, 0, stream>>>(xpw, xpw_pad, 56*768, 128*768);
  k_cvt<<<(294912+255)/256, 256, 0, stream>>>(outw, outw_b, 294912);
  k_cvt<<<(589824+255)/256, 256, 0, stream>>>(fc1w, fc1w_b, 589824);
  k_cvt<<<(589824+255)/256, 256, 0, stream>>>(fc2w, fc2w_b, 589824);

  k_transpose<<<dim3(72,12,8), dim3(32,8), 0, stream>>>(x, XS);
  k_lnstats<<<MROWS, 64, 0, stream>>>(XS, n1g,n1b,n2g,n2b, apw,apb, MEANR, RSTDR, XN2b, SCORES);
  k_softmax_L<<<BB*NHD, 256, 0, stream>>>(SCORES);
  k_wpool<<<(MROWS+255)/256, 256, 0, stream>>>(SCORES, WPOOL);
  k_zero<<<(BB*DIMC+255)/256, 256, 0, stream>>>(GC, BB*DIMC);
  k_gc<<<dim3(BB,12), 384, 0, stream>>>(WPOOL, XS, MEANR, RSTDR, n1g, n1b, GC);
  k_mod1<<<dim3(BB,12), 64, 0, stream>>>(GC, modw1, modb1, MODH);
  k_mod2<<<dim3(BB,6), 64, 0, stream>>>(MODH, modw2, modb2, MOD);

  // in_proj (two halves): XMb / Zb = XN2 @ inw^T + inb   (K=384, N=768 each)
  k_mgemm<0><<<dim3(144,6), 256, 0, stream>>>(XN2b, inw_b, inb, XMb, 384, 768, nullptr);
  k_mgemm<0><<<dim3(144,6), 256, 0, stream>>>(XN2b, inw_b+(size_t)768*384, inb+768, Zb, 384, 768, nullptr);
  // conv + silu -> Ub (bf16, in d_out; overwrites XN2b which is now dead)
  k_conv<<<(int)(((size_t)MROWS*DINN+255)/256), 256, 0, stream>>>(XMb, convw, convb, Ub);
  // dbc = u @ xp_w^T (K=768, N=56 with guard; W padded to 128 rows)
  k_mgemm<4><<<dim3(144,1), 256, 0, stream>>>(Ub, xpw_pad, nullptr, DBC, 768, 56, nullptr);
  // delta = softplus(dbc[:, :24] @ dt_w^T + dt_b) -> DELTAb bf16
  k_dtgemm<<<dim3(288,12), 256, 0, stream>>>(DBC, dtw, dtb, DELTAb);
  // chunked scan (APROD/HL overlay the dead XMb region)
  k_scan1<<<BB*48*NCH, 256, 0, stream>>>(DELTAb, Ub, DBC, Alog, APROD, HL);
  k_scan2<<<384, 256, 0, stream>>>(APROD, HL);
  k_scan3<<<BB*48*NCH, 256, 0, stream>>>(DELTAb, Ub, DBC, Zb, Alog, Dp, HL);
  // XS += (yact @ out_w^T + out_b) * (1 + mod)   (K=768, N=384)
  k_mgemm<2><<<dim3(144,3), 256, 0, stream>>>(DELTAb, outw_b, outb, XS, 768, 384, MOD);
  // Hb = LN3(XS)  (bf16, into d_out; Ub dead now)
  k_ln3<<<MROWS, 64, 0, stream>>>(XS, n3g, n3b, Hb);
  // F1b = gelu(H @ fc1_w^T + fc1_b)   (K=384, N=1536; overlays BIG)
  k_mgemm<1><<<dim3(144,12), 256, 0, stream>>>(Hb, fc1w_b, fc1b, F1b, 384, 1536, nullptr);
  // d_out = transpose(XS + F1 @ fc2_w^T + fc2_b)   (K=1536, N=384)
  k_mgemm<3><<<dim3(144,3), 256, 0, stream>>>(F1b, fc2w_b, fc2b, d_out, 1536, 384, XS);
}

// Round 4
// 683.503 us; speedup vs baseline: 3.5321x; 1.2507x over previous
//
#include <hip/hip_runtime.h>
#include <math.h>

#define DIMC 384
#define NHD 8
#define NSTATE 16
#define DINN 768
#define DTRK 24
#define BB 8
#define LSEQ 2304
#define MROWS (BB*LSEQ)   // 18432
#define NCH 32
#define TCH 72            // LSEQ / NCH
#define L2E 1.44269504f

typedef unsigned short u16;
typedef short bf16x8 __attribute__((ext_vector_type(8)));
typedef float f32x4 __attribute__((ext_vector_type(4)));

__device__ __forceinline__ float sigmoid_(float x){ return 1.f/(1.f+__expf(-x)); }
__device__ __forceinline__ float silu_(float x){ return x*sigmoid_(x); }
__device__ __forceinline__ float softplus_(float x){ return (x>20.f)?x:log1pf(__expf(x)); }
__device__ __forceinline__ float gelu_(float x){
  float x3=x*x*x;
  return 0.5f*x*(1.f+tanhf(0.7978845608028654f*(x+0.044715f*x3)));
}
__device__ __forceinline__ float bfu2f(u16 u){
  union{unsigned int i; float f;} c; c.i=((unsigned int)u)<<16; return c.f;
}
__device__ __forceinline__ u16 f2bfu(float f){
  union{float f; unsigned int i;} c; c.f=f;
  unsigned int r = c.i + 0x7FFFu + ((c.i>>16)&1u);
  return (u16)(r>>16);
}
// async global->LDS, 16B per lane; dest must be wave-uniform base + lane*16
__device__ __forceinline__ void gl_lds16(const u16* g, u16* l){
  __builtin_amdgcn_global_load_lds((__attribute__((address_space(1))) void*)g,
      (__attribute__((address_space(3))) void*)l, 16, 0, 0);
}

// ---------------- weight f32 -> bf16 convert ----------------
__global__ void k_cvt(const float* __restrict__ s, u16* __restrict__ d, int n){
  int i=blockIdx.x*256+threadIdx.x; if(i<n) d[i]=f2bfu(s[i]);
}
__global__ void k_cvtpad(const float* __restrict__ s, u16* __restrict__ d, int nsrc, int ntot){
  int i=blockIdx.x*256+threadIdx.x; if(i<ntot) d[i] = (i<nsrc)? f2bfu(s[i]) : (u16)0;
}

// ---------------- transpose (B,C,L) -> (B,L,C) ----------------
__global__ void k_transpose(const float* __restrict__ x, float* __restrict__ xs){
  __shared__ float tile[32][33];
  int b = blockIdx.z;
  int t0 = blockIdx.x*32, c0 = blockIdx.y*32;
  int tx = threadIdx.x, ty = threadIdx.y; // 32 x 8
  const float* xb = x + (size_t)b*DIMC*LSEQ;
  #pragma unroll
  for(int q=0;q<4;q++)
    tile[ty+q*8][tx] = xb[(size_t)(c0+ty+q*8)*LSEQ + t0+tx];
  __syncthreads();
  float* xsb = xs + (size_t)b*LSEQ*DIMC;
  #pragma unroll
  for(int q=0;q<4;q++)
    xsb[(size_t)(t0+ty+q*8)*DIMC + c0+tx] = tile[tx][ty+q*8];
}

// -------- LN stats + LN2 (bf16 out) + attention scores --------
__global__ __launch_bounds__(64) void k_lnstats(const float* __restrict__ xs,
   const float* __restrict__ g1,const float* __restrict__ b1,
   const float* __restrict__ g2,const float* __restrict__ b2,
   const float* __restrict__ apw,const float* __restrict__ apb,
   float* __restrict__ meanr, float* __restrict__ rstdr,
   u16* __restrict__ xn2, float* __restrict__ scores){
  int row = blockIdx.x;
  int lane = threadIdx.x;
  const float* xr = xs + (size_t)row*DIMC;
  float v[6];
  float s=0.f, s2=0.f;
  #pragma unroll
  for(int i=0;i<6;i++){ v[i]=xr[lane+i*64]; s+=v[i]; s2+=v[i]*v[i]; }
  #pragma unroll
  for(int m=32;m>=1;m>>=1){ s += __shfl_xor(s,m); s2 += __shfl_xor(s2,m); }
  float mean = s*(1.f/DIMC);
  float var  = s2*(1.f/DIMC)-mean*mean;
  float rstd = rsqrtf(var+1e-5f);
  if(lane==0){ meanr[row]=mean; rstdr[row]=rstd; }
  float xv1[6];
  #pragma unroll
  for(int i=0;i<6;i++){
    int c = lane+i*64;
    float nx = (v[i]-mean)*rstd;
    xv1[i] = nx*g1[c]+b1[c];
    xn2[(size_t)row*DIMC+c] = f2bfu(nx*g2[c]+b2[c]);
  }
  #pragma unroll
  for(int h=0;h<NHD;h++){
    float p=0.f;
    #pragma unroll
    for(int i=0;i<6;i++) p += xv1[i]*apw[h*DIMC+lane+i*64];
    #pragma unroll
    for(int m=32;m>=1;m>>=1) p += __shfl_xor(p,m);
    if(lane==0) scores[(size_t)row*NHD+h]=p+apb[h];
  }
}

// ---------------- softmax over L per (b,h), in-place ----------------
__global__ __launch_bounds__(256) void k_softmax_L(float* __restrict__ sc){
  int bh = blockIdx.x; int b = bh>>3, h = bh&7;
  int tid = threadIdx.x;
  __shared__ float red[8];
  const size_t base = (size_t)b*LSEQ*NHD + h;
  float mx = -1e30f;
  for(int l=tid;l<LSEQ;l+=256) mx = fmaxf(mx, sc[base + (size_t)l*NHD]);
  #pragma unroll
  for(int m=32;m>=1;m>>=1) mx = fmaxf(mx, __shfl_xor(mx,m));
  if((tid&63)==0) red[tid>>6]=mx;
  __syncthreads();
  mx = fmaxf(fmaxf(red[0],red[1]),fmaxf(red[2],red[3]));
  float sum=0.f;
  for(int l=tid;l<LSEQ;l+=256) sum += __expf(sc[base+(size_t)l*NHD]-mx);
  #pragma unroll
  for(int m=32;m>=1;m>>=1) sum += __shfl_xor(sum,m);
  if((tid&63)==0) red[4+(tid>>6)]=sum;
  __syncthreads();
  float inv = 1.f/(red[4]+red[5]+red[6]+red[7]);
  for(int l=tid;l<LSEQ;l+=256){
    size_t idx = base+(size_t)l*NHD;
    sc[idx] = __expf(sc[idx]-mx)*inv;
  }
}

__global__ void k_wpool(const float* __restrict__ attn, float* __restrict__ w){
  int i = blockIdx.x*256+threadIdx.x;
  if(i<MROWS){
    const float* a = attn+(size_t)i*NHD;
    float s=0.f;
    #pragma unroll
    for(int h=0;h<NHD;h++) s+=a[h];
    w[i]=s*0.125f;
  }
}

__global__ void k_zero(float* __restrict__ p, int n){
  int i=blockIdx.x*256+threadIdx.x; if(i<n)p[i]=0.f;
}

// gc[b,c] = sum_l w[b,l]*xn1[b,l,c]  (xn1 recomputed from XS + mean/rstd)
__global__ __launch_bounds__(384) void k_gc(const float* __restrict__ w,
    const float* __restrict__ xs, const float* __restrict__ meanr,
    const float* __restrict__ rstdr, const float* __restrict__ g1,
    const float* __restrict__ b1, float* __restrict__ gc){
  int b = blockIdx.x; int chunk = blockIdx.y; int c = threadIdx.x;
  int l0 = chunk*192;
  float acc=0.f, accw=0.f;
  for(int l=0;l<192;l++){
    int row = b*LSEQ + l0+l;
    float ww = w[row];
    acc  += ww*(xs[(size_t)row*DIMC+c]-meanr[row])*rstdr[row];
    accw += ww;
  }
  atomicAdd(&gc[b*DIMC+c], acc*g1[c]+accw*b1[c]);
}

__global__ __launch_bounds__(64) void k_mod1(const float* __restrict__ gc,
    const float* __restrict__ w1, const float* __restrict__ b1, float* __restrict__ h){
  int b = blockIdx.x; int n = blockIdx.y*64+threadIdx.x;
  const float* g = gc + b*DIMC;
  const float* wr = w1 + (size_t)n*DIMC;
  float acc=0.f;
  for(int k=0;k<DIMC;k++) acc += g[k]*wr[k];
  h[b*768+n] = silu_(acc+b1[n]);
}
__global__ __launch_bounds__(64) void k_mod2(const float* __restrict__ h,
    const float* __restrict__ w2, const float* __restrict__ b2, float* __restrict__ mod){
  int b = blockIdx.x; int n = blockIdx.y*64+threadIdx.x;
  const float* hh = h + b*768;
  const float* wr = w2 + (size_t)n*768;
  float acc=0.f;
  for(int k=0;k<768;k++) acc += hh[k]*wr[k];
  mod[b*DIMC+n] = acc+b2[n];
}

// =====================  bf16 MFMA GEMM (global_load_lds staging)  ==========
// out = epi(A @ W^T + bias).  A:(M,K) bf16 row-major, W:(N,K) bf16 row-major.
// Tile 128x128, BK=32, 256 threads = 4 waves (2x2 of 64x64).
// EPI: 0 bf16 store, 1 gelu->bf16, 2 f32: out += v*(1+aux[b,col]) in place,
//      3 final: d_out[(b*C+col)*L+t]=aux[row,col]+v (float4),
//      4 f32 store col<N guard, 5 split bf16: col<768 -> outp else outp2.
template<int EPI>
__global__ __launch_bounds__(256,2) void k_mgemm(
    const u16* __restrict__ A, const u16* __restrict__ W,
    const float* __restrict__ bias, void* __restrict__ outp,
    int K, int N, const float* __restrict__ aux, void* __restrict__ outp2)
{
  __shared__ u16 lA[4096];   // [kc:4][row:128][8]  (8 KB)
  __shared__ u16 lB[4096];
  int tid = threadIdx.x;
  int m0 = blockIdx.x*128, n0 = blockIdx.y*128;
  int wid = tid>>6, lane = tid&63;
  int wr = wid>>1, wc = wid&1;
  int lrow = lane&15, lk = lane>>4;
  f32x4 acc[4][4];
  #pragma unroll
  for(int i=0;i<4;i++)
    #pragma unroll
    for(int j=0;j<4;j++){ acc[i][j][0]=0.f; acc[i][j][1]=0.f; acc[i][j][2]=0.f; acc[i][j][3]=0.f; }

  // staging map: flat = q*256 + tid; kc = flat>>7 (0..3), row = flat&127.
  // LDS dest = flat*16B (wave-uniform base + lane*16). Global src per-lane.
  int r0 = tid & 127, k0 = tid >> 7;        // q=0: kc 0..1
  const u16* Ag0 = A + (size_t)(m0+r0)*K + k0*8;
  const u16* Ag1 = A + (size_t)(m0+r0)*K + (k0+2)*8;
  const u16* Bg0 = W + (size_t)(n0+r0)*K + k0*8;
  const u16* Bg1 = W + (size_t)(n0+r0)*K + (k0+2)*8;
  u16* lAd0 = lA + tid*8;  u16* lAd1 = lA + 2048 + tid*8;
  u16* lBd0 = lB + tid*8;  u16* lBd1 = lB + 2048 + tid*8;

  for(int kb=0; kb<K; kb+=32){
    __syncthreads();
    gl_lds16(Ag0 + kb, lAd0);
    gl_lds16(Ag1 + kb, lAd1);
    gl_lds16(Bg0 + kb, lBd0);
    gl_lds16(Bg1 + kb, lBd1);
    __syncthreads();
    bf16x8 af[4], bfr[4];
    #pragma unroll
    for(int i=0;i<4;i++){
      af[i]  = *reinterpret_cast<const bf16x8*>(&lA[(lk*128 + wr*64 + i*16 + lrow)*8]);
      bfr[i] = *reinterpret_cast<const bf16x8*>(&lB[(lk*128 + wc*64 + i*16 + lrow)*8]);
    }
    #pragma unroll
    for(int i=0;i<4;i++)
      #pragma unroll
      for(int j=0;j<4;j++)
        acc[i][j] = __builtin_amdgcn_mfma_f32_16x16x32_bf16(af[i], bfr[j], acc[i][j], 0,0,0);
  }

  #pragma unroll
  for(int i=0;i<4;i++){
    int row = m0 + wr*64 + i*16 + lk*4;
    #pragma unroll
    for(int j=0;j<4;j++){
      int col = n0 + wc*64 + j*16 + lrow;
      float bc = bias ? bias[col] : 0.f;
      f32x4 v = acc[i][j];
      if(EPI==0){
        u16* o = (u16*)outp;
        #pragma unroll
        for(int r=0;r<4;r++) o[(size_t)(row+r)*N + col] = f2bfu(v[r]+bc);
      } else if(EPI==1){
        u16* o = (u16*)outp;
        #pragma unroll
        for(int r=0;r<4;r++) o[(size_t)(row+r)*N + col] = f2bfu(gelu_(v[r]+bc));
      } else if(EPI==2){
        float* o = (float*)outp;
        int bi = row/LSEQ;
        float sc = 1.f + aux[bi*DIMC + col];
        #pragma unroll
        for(int r=0;r<4;r++) o[(size_t)(row+r)*DIMC + col] += (v[r]+bc)*sc;
      } else if(EPI==3){
        float* o = (float*)outp;
        int bi = row/LSEQ, t = row - bi*LSEQ;
        float4 s;
        s.x = aux[(size_t)(row+0)*DIMC+col] + v[0] + bc;
        s.y = aux[(size_t)(row+1)*DIMC+col] + v[1] + bc;
        s.z = aux[(size_t)(row+2)*DIMC+col] + v[2] + bc;
        s.w = aux[(size_t)(row+3)*DIMC+col] + v[3] + bc;
        *reinterpret_cast<float4*>(&o[((size_t)(bi*DIMC+col))*LSEQ + t]) = s;
      } else if(EPI==4){
        float* o = (float*)outp;
        if(col < N){
          #pragma unroll
          for(int r=0;r<4;r++) o[(size_t)(row+r)*N + col] = v[r]+bc;
        }
      } else { // EPI==5: split into two (M,768) bf16 outputs
        u16* o = (col < 768) ? (u16*)outp : (u16*)outp2;
        int cc = (col < 768) ? col : col - 768;
        #pragma unroll
        for(int r=0;r<4;r++) o[(size_t)(row+r)*768 + cc] = f2bfu(v[r]+bc);
      }
    }
  }
}

// ---------------- causal depthwise conv K=4 + silu (bf16 in, bf16 out) ----------------
__global__ void k_conv(const u16* __restrict__ xm, const float* __restrict__ cw,
                       const float* __restrict__ cb, u16* __restrict__ u){
  size_t i = (size_t)blockIdx.x*256+threadIdx.x;
  if(i >= (size_t)MROWS*DINN) return;
  int d = (int)(i % DINN);
  int r = (int)(i / DINN);
  int t = r % LSEQ;
  float acc = cb[d];
  #pragma unroll
  for(int k=0;k<4;k++){
    int tt = t + k - 3;
    if(tt>=0) acc += bfu2f(xm[(size_t)(r - t + tt)*DINN + d])*cw[d*4+k];
  }
  u[i] = f2bfu(silu_(acc));
}

// ---------------- small-K GEMM for delta (K=24) + softplus, bf16 out ----------------
__global__ __launch_bounds__(256) void k_dtgemm(const float* __restrict__ DBC,
    const float* __restrict__ dtw, const float* __restrict__ dtb,
    u16* __restrict__ delta){
  __shared__ float As[64][24];
  __shared__ float Ws[64][24];
  int tid = threadIdx.x;
  int m0 = blockIdx.x*64, n0 = blockIdx.y*64;
  for(int j=tid;j<64*24;j+=256){
    int rr=j/24, kk=j-rr*24;
    As[rr][kk]=DBC[(size_t)(m0+rr)*56+kk];
    Ws[rr][kk]=dtw[(size_t)(n0+rr)*24+kk];
  }
  __syncthreads();
  int tx=tid&15, ty=tid>>4;
  float acc[4][4]={};
  for(int k=0;k<24;k++){
    float a[4],w[4];
    #pragma unroll
    for(int i=0;i<4;i++){a[i]=As[ty*4+i][k]; w[i]=Ws[tx*4+i][k];}
    #pragma unroll
    for(int i=0;i<4;i++)
      #pragma unroll
      for(int j=0;j<4;j++) acc[i][j]+=a[i]*w[j];
  }
  #pragma unroll
  for(int i=0;i<4;i++){
    int row=m0+ty*4+i;
    #pragma unroll
    for(int j=0;j<4;j++){
      int col=n0+tx*4+j;
      delta[(size_t)row*DINN+col]=f2bfu(softplus_(acc[i][j]+dtb[col]));
    }
  }
}

// ============ chunked selective scan, d-per-thread layout ============
// grid = BB*NCH*3 blocks of 256 threads; thread owns (b, ch, d) with h[16] in regs.
// pass 1: h_local (from 0) + S = sum dt over chunk.
__global__ __launch_bounds__(256) void k_scan1(
  const u16* __restrict__ dt_, const u16* __restrict__ u_,
  const float* __restrict__ dbc, const float* __restrict__ alog,
  float* __restrict__ ssum, float* __restrict__ hloc)
{
  __shared__ float Bsh[TCH][16];
  int bid = blockIdx.x;
  int b = bid/(NCH*3); int rem = bid%(NCH*3); int ch = rem/3; int dblk = rem%3;
  int tid = threadIdx.x; int d = dblk*256 + tid;
  size_t rbase = (size_t)b*LSEQ + (size_t)ch*TCH;
  for(int j=tid; j<TCH*16; j+=256){
    int row=j>>4, n=j&15;
    Bsh[row][n] = dbc[(rbase+row)*56 + DTRK + n];
  }
  float Acl2[16], h[16];
  #pragma unroll
  for(int n=0;n<16;n++){
    Acl2[n] = -__expf(alog[(size_t)d*16+n])*L2E;
    h[n]=0.f;
  }
  float S=0.f;
  const u16* dtp = dt_ + rbase*DINN + d;
  const u16* up  = u_  + rbase*DINN + d;
  __syncthreads();
  for(int t=0;t<TCH;t++){
    float dt = bfu2f(dtp[(size_t)t*DINN]);
    float uv = bfu2f(up[(size_t)t*DINN]);
    float G = dt*uv;
    S += dt;
    const float4* b4 = (const float4*)Bsh[t];
    float4 B0=b4[0],B1=b4[1],B2=b4[2],B3=b4[3];
    float Bv[16]={B0.x,B0.y,B0.z,B0.w,B1.x,B1.y,B1.z,B1.w,
                  B2.x,B2.y,B2.z,B2.w,B3.x,B3.y,B3.z,B3.w};
    #pragma unroll
    for(int n=0;n<16;n++)
      h[n] = h[n]*exp2f(dt*Acl2[n]) + G*Bv[n];
  }
  ssum[((size_t)b*NCH+ch)*DINN + d] = S;
  float* hp = hloc + (((size_t)b*NCH+ch)*DINN + d)*16;
  #pragma unroll
  for(int n=0;n<16;n++) hp[n] = h[n];
}

// pass 2: sequential combine over chunks; hl becomes h_in per chunk.
__global__ __launch_bounds__(256) void k_scan2(
  const float* __restrict__ ssum, const float* __restrict__ alog,
  float* __restrict__ hl)
{
  int gid = blockIdx.x*256+threadIdx.x;   // B*DINN*16
  int n = gid & 15; int d = (gid>>4)%DINN; int b = gid/(DINN*NSTATE);
  float Acl2 = -__expf(alog[(size_t)d*16+n])*L2E;
  float hin=0.f;
  for(int ch=0; ch<NCH; ch++){
    size_t sidx = ((size_t)b*NCH+ch)*DINN + d;
    size_t idx  = sidx*16 + n;
    float a = exp2f(ssum[sidx]*Acl2);
    float hold = hl[idx];
    hl[idx] = hin;
    hin = a*hin + hold;
  }
}

// pass 3: replay chunk from h_in, write y=(h.C + u*Dp)*silu(z) over u (in place).
__global__ __launch_bounds__(256) void k_scan3(
  const u16* __restrict__ dt_, u16* uy, const u16* __restrict__ z_,
  const float* __restrict__ dbc, const float* __restrict__ alog,
  const float* __restrict__ Dp, const float* __restrict__ hin)
{
  __shared__ float BC[TCH][32];
  int bid = blockIdx.x;
  int b = bid/(NCH*3); int rem = bid%(NCH*3); int ch = rem/3; int dblk = rem%3;
  int tid = threadIdx.x; int d = dblk*256 + tid;
  size_t rbase = (size_t)b*LSEQ + (size_t)ch*TCH;
  for(int j=tid; j<TCH*32; j+=256){
    int row=j>>5, c=j&31;
    BC[row][c] = dbc[(rbase+row)*56 + DTRK + c];
  }
  float Acl2[16], h[16];
  const float* hp = hin + (((size_t)b*NCH+ch)*DINN + d)*16;
  #pragma unroll
  for(int n=0;n<16;n++){
    Acl2[n] = -__expf(alog[(size_t)d*16+n])*L2E;
    h[n] = hp[n];
  }
  float Dv = Dp[d];
  const u16* dtp = dt_ + rbase*DINN + d;
  u16*       uyp = uy  + rbase*DINN + d;
  const u16* zp  = z_  + rbase*DINN + d;
  __syncthreads();
  for(int t=0;t<TCH;t++){
    float dt = bfu2f(dtp[(size_t)t*DINN]);
    float uv = bfu2f(uyp[(size_t)t*DINN]);
    float zv = bfu2f(zp[(size_t)t*DINN]);
    float G = dt*uv;
    const float4* bc4 = (const float4*)BC[t];
    float4 B0=bc4[0],B1=bc4[1],B2=bc4[2],B3=bc4[3];
    float4 C0=bc4[4],C1=bc4[5],C2=bc4[6],C3=bc4[7];
    float Bv[16]={B0.x,B0.y,B0.z,B0.w,B1.x,B1.y,B1.z,B1.w,
                  B2.x,B2.y,B2.z,B2.w,B3.x,B3.y,B3.z,B3.w};
    float Cv[16]={C0.x,C0.y,C0.z,C0.w,C1.x,C1.y,C1.z,C1.w,
                  C2.x,C2.y,C2.z,C2.w,C3.x,C3.y,C3.z,C3.w};
    #pragma unroll
    for(int n=0;n<16;n++)
      h[n] = h[n]*exp2f(dt*Acl2[n]) + G*Bv[n];
    float y0=0.f,y1=0.f,y2=0.f,y3=0.f;
    #pragma unroll
    for(int n=0;n<16;n+=4){
      y0 += h[n+0]*Cv[n+0];
      y1 += h[n+1]*Cv[n+1];
      y2 += h[n+2]*Cv[n+2];
      y3 += h[n+3]*Cv[n+3];
    }
    float y = (y0+y1)+(y2+y3);
    float sz = silu_(zv);
    uyp[(size_t)t*DINN] = f2bfu((y + uv*Dv)*sz);
  }
}

// ---------------- LN3, bf16 out ----------------
__global__ __launch_bounds__(64) void k_ln3(const float* __restrict__ xin,
    const float* __restrict__ g, const float* __restrict__ bb, u16* __restrict__ xout){
  int row = blockIdx.x;
  int lane = threadIdx.x;
  const float* xr = xin + (size_t)row*DIMC;
  float v[6];
  float s=0.f, s2=0.f;
  #pragma unroll
  for(int i=0;i<6;i++){ v[i]=xr[lane+i*64]; s+=v[i]; s2+=v[i]*v[i]; }
  #pragma unroll
  for(int m=32;m>=1;m>>=1){ s += __shfl_xor(s,m); s2 += __shfl_xor(s2,m); }
  float mean = s*(1.f/DIMC);
  float var  = s2*(1.f/DIMC)-mean*mean;
  float rstd = rsqrtf(var+1e-5f);
  #pragma unroll
  for(int i=0;i<6;i++){
    int c = lane+i*64;
    xout[(size_t)row*DIMC+c] = f2bfu((v[i]-mean)*rstd*g[c]+bb[c]);
  }
}

extern "C" void kernel_launch(void* const* d_in, const int* in_sizes, int n_in,
                              void* d_out, int out_size, void* d_ws, size_t ws_size,
                              hipStream_t stream)
{
  const float* x     = (const float*)d_in[0];
  const float* n1g   = (const float*)d_in[1];
  const float* n1b   = (const float*)d_in[2];
  const float* apw   = (const float*)d_in[3];
  const float* apb   = (const float*)d_in[4];
  const float* n2g   = (const float*)d_in[5];
  const float* n2b   = (const float*)d_in[6];
  const float* inw   = (const float*)d_in[7];
  const float* inb   = (const float*)d_in[8];
  const float* convw = (const float*)d_in[9];
  const float* convb = (const float*)d_in[10];
  const float* xpw   = (const float*)d_in[11];
  const float* dtw   = (const float*)d_in[12];
  const float* dtb   = (const float*)d_in[13];
  const float* Alog  = (const float*)d_in[14];
  const float* Dp    = (const float*)d_in[15];
  const float* outw  = (const float*)d_in[16];
  const float* outb  = (const float*)d_in[17];
  const float* modw1 = (const float*)d_in[18];
  const float* modb1 = (const float*)d_in[19];
  const float* modw2 = (const float*)d_in[20];
  const float* modb2 = (const float*)d_in[21];
  const float* n3g   = (const float*)d_in[22];
  const float* n3b   = (const float*)d_in[23];
  const float* fc1w  = (const float*)d_in[24];
  const float* fc1b  = (const float*)d_in[25];
  const float* fc2w  = (const float*)d_in[26];
  const float* fc2b  = (const float*)d_in[27];

  // ---- workspace layout (f32 slots), total 30,640,128 f = 122.6 MB ----
  float* ws = (float*)d_ws;
  float* XS    = ws;                       // 7,077,888 f
  float* R1    = ws + 7077888;             // 14,155,776 f multi-use region:
  //  phase A: XMb bf16 (M*768) in f[0..7.08M)
  //  phase B: DTb bf16 over XMb; SSUM f[7.08M..7.27M); HL f[7.27M..10.42M)
  //  phase C: F1b bf16 (M*1536) = full region
  u16*   XMb   = (u16*)R1;
  u16*   DTb   = (u16*)R1;
  float* SSUM  = R1 + 7077888;             // 196,608 f
  float* HL    = R1 + 7274496;             // 3,145,728 f
  u16*   F1b   = (u16*)R1;
  u16*   Zb    = (u16*)(ws + 21233664);    // 14,155,776 u16 (= 7,077,888 f)
  float* DBC   = ws + 28311552;            // 1,032,192 f
  float* WB    = ws + 29343744;            // bf16 weights, 1,081,344 f slots
  u16*   inw_b   = (u16*)WB;                     // 589,824 sh
  u16*   xpw_pad = inw_b + 589824;               // 98,304 sh (128x768, rows 56+ zero)
  u16*   outw_b  = xpw_pad + 98304;              // 294,912 sh
  u16*   fc1w_b  = outw_b + 294912;              // 589,824 sh
  u16*   fc2w_b  = fc1w_b + 589824;              // 589,824 sh
  float* SCORES= ws + 30425088;            // 147,456 f
  float* WPOOL = ws + 30572544;            // 18,432
  float* MEANR = ws + 30590976;            // 18,432
  float* RSTDR = ws + 30609408;            // 18,432
  float* GC    = ws + 30627840;            // 3,072
  float* MODH  = ws + 30630912;            // 6,144
  float* MOD   = ws + 30637056;            // 3,072
  (void)ws_size; (void)n_in; (void)in_sizes; (void)out_size;

  // d_out as scratch: XN2b bf16 -> Ub bf16 -> Y bf16 (in-place over Ub) -> Hb bf16
  u16* XN2b = (u16*)d_out;
  u16* Ub   = (u16*)d_out;
  u16* Hb   = (u16*)d_out;

  // weight conversion
  k_cvt<<<(589824+255)/256, 256, 0, stream>>>(inw,  inw_b,  589824);
  k_cvtpad<<<(98304+255)/256, 256, 0, stream>>>(xpw, xpw_pad, 56*768, 128*768);
  k_cvt<<<(294912+255)/256, 256, 0, stream>>>(outw, outw_b, 294912);
  k_cvt<<<(589824+255)/256, 256, 0, stream>>>(fc1w, fc1w_b, 589824);
  k_cvt<<<(589824+255)/256, 256, 0, stream>>>(fc2w, fc2w_b, 589824);

  k_transpose<<<dim3(72,12,8), dim3(32,8), 0, stream>>>(x, XS);
  k_lnstats<<<MROWS, 64, 0, stream>>>(XS, n1g,n1b,n2g,n2b, apw,apb, MEANR, RSTDR, XN2b, SCORES);
  k_softmax_L<<<BB*NHD, 256, 0, stream>>>(SCORES);
  k_wpool<<<(MROWS+255)/256, 256, 0, stream>>>(SCORES, WPOOL);
  k_zero<<<(BB*DIMC+255)/256, 256, 0, stream>>>(GC, BB*DIMC);
  k_gc<<<dim3(BB,12), 384, 0, stream>>>(WPOOL, XS, MEANR, RSTDR, n1g, n1b, GC);
  k_mod1<<<dim3(BB,12), 64, 0, stream>>>(GC, modw1, modb1, MODH);
  k_mod2<<<dim3(BB,6), 64, 0, stream>>>(MODH, modw2, modb2, MOD);

  // in_proj fused: [XMb | Zb] = XN2 @ inw^T + inb   (K=384, N=1536, split store)
  k_mgemm<5><<<dim3(144,12), 256, 0, stream>>>(XN2b, inw_b, inb, XMb, 384, 1536, nullptr, Zb);
  // conv + silu -> Ub (bf16, in d_out; XN2b dead)
  k_conv<<<(int)(((size_t)MROWS*DINN+255)/256), 256, 0, stream>>>(XMb, convw, convb, Ub);
  // dbc = u @ xp_w^T (K=768, N=56; W padded to 128 rows)
  k_mgemm<4><<<dim3(144,1), 256, 0, stream>>>(Ub, xpw_pad, nullptr, DBC, 768, 56, nullptr, nullptr);
  // delta = softplus(dbc[:, :24] @ dt_w^T + dt_b) -> DTb (over dead XMb)
  k_dtgemm<<<dim3(288,12), 256, 0, stream>>>(DBC, dtw, dtb, DTb);
  // chunked scan (d-per-thread)
  k_scan1<<<BB*NCH*3, 256, 0, stream>>>(DTb, Ub, DBC, Alog, SSUM, HL);
  k_scan2<<<384, 256, 0, stream>>>(SSUM, Alog, HL);
  k_scan3<<<BB*NCH*3, 256, 0, stream>>>(DTb, Ub, Zb, DBC, Alog, Dp, HL);
  // XS += (y @ out_w^T + out_b) * (1 + mod)   (K=768, N=384); Y lives in Ub slot
  k_mgemm<2><<<dim3(144,3), 256, 0, stream>>>(Ub, outw_b, outb, XS, 768, 384, MOD, nullptr);
  // Hb = LN3(XS)  (bf16, into d_out; Y dead)
  k_ln3<<<MROWS, 64, 0, stream>>>(XS, n3g, n3b, Hb);
  // F1b = gelu(H @ fc1_w^T + fc1_b)   (K=384, N=1536; overlays R1)
  k_mgemm<1><<<dim3(144,12), 256, 0, stream>>>(Hb, fc1w_b, fc1b, F1b, 384, 1536, nullptr, nullptr);
  // d_out = transpose(XS + F1 @ fc2_w^T + fc2_b)   (K=1536, N=384)
  k_mgemm<3><<<dim3(144,3), 256, 0, stream>>>(F1b, fc2w_b, fc2b, d_out, 1536, 384, XS, nullptr);
}

// Round 5
// 571.394 us; speedup vs baseline: 4.2251x; 1.1962x over previous
//
#include <hip/hip_runtime.h>
#include <math.h>

#define DIMC 384
#define NHD 8
#define NSTATE 16
#define DINN 768
#define DTRK 24
#define BB 8
#define LSEQ 2304
#define MROWS (BB*LSEQ)   // 18432
#define NCH 64
#define TCH 36            // LSEQ / NCH
#define L2E 1.44269504f

typedef unsigned short u16;
typedef short bf16x8 __attribute__((ext_vector_type(8)));
typedef float f32x4 __attribute__((ext_vector_type(4)));

__device__ __forceinline__ float sigmoid_(float x){ return 1.f/(1.f+__expf(-x)); }
__device__ __forceinline__ float silu_(float x){ return x*sigmoid_(x); }
__device__ __forceinline__ float softplus_(float x){ return (x>20.f)?x:log1pf(__expf(x)); }
__device__ __forceinline__ float gelu_(float x){
  float x3=x*x*x;
  return 0.5f*x*(1.f+tanhf(0.7978845608028654f*(x+0.044715f*x3)));
}
__device__ __forceinline__ float bfu2f(u16 u){
  union{unsigned int i; float f;} c; c.i=((unsigned int)u)<<16; return c.f;
}
__device__ __forceinline__ u16 f2bfu(float f){
  union{float f; unsigned int i;} c; c.f=f;
  unsigned int r = c.i + 0x7FFFu + ((c.i>>16)&1u);
  return (u16)(r>>16);
}
// async global->LDS, 16B per lane; dest must be wave-uniform base + lane*16
__device__ __forceinline__ void gl_lds16(const u16* g, u16* l){
  __builtin_amdgcn_global_load_lds((__attribute__((address_space(1))) void*)g,
      (__attribute__((address_space(3))) void*)l, 16, 0, 0);
}

// ---------------- weight f32 -> bf16 convert ----------------
__global__ void k_cvt(const float* __restrict__ s, u16* __restrict__ d, int n){
  int i=blockIdx.x*256+threadIdx.x; if(i<n) d[i]=f2bfu(s[i]);
}
__global__ void k_cvtpad(const float* __restrict__ s, u16* __restrict__ d, int nsrc, int ntot){
  int i=blockIdx.x*256+threadIdx.x; if(i<ntot) d[i] = (i<nsrc)? f2bfu(s[i]) : (u16)0;
}

// ---------------- transpose (B,C,L) -> (B,L,C) ----------------
__global__ void k_transpose(const float* __restrict__ x, float* __restrict__ xs){
  __shared__ float tile[32][33];
  int b = blockIdx.z;
  int t0 = blockIdx.x*32, c0 = blockIdx.y*32;
  int tx = threadIdx.x, ty = threadIdx.y; // 32 x 8
  const float* xb = x + (size_t)b*DIMC*LSEQ;
  #pragma unroll
  for(int q=0;q<4;q++)
    tile[ty+q*8][tx] = xb[(size_t)(c0+ty+q*8)*LSEQ + t0+tx];
  __syncthreads();
  float* xsb = xs + (size_t)b*LSEQ*DIMC;
  #pragma unroll
  for(int q=0;q<4;q++)
    xsb[(size_t)(t0+ty+q*8)*DIMC + c0+tx] = tile[tx][ty+q*8];
}

// -------- LN stats + LN2 (bf16 out) + attention scores --------
__global__ __launch_bounds__(64) void k_lnstats(const float* __restrict__ xs,
   const float* __restrict__ g1,const float* __restrict__ b1,
   const float* __restrict__ g2,const float* __restrict__ b2,
   const float* __restrict__ apw,const float* __restrict__ apb,
   float* __restrict__ meanr, float* __restrict__ rstdr,
   u16* __restrict__ xn2, float* __restrict__ scores){
  int row = blockIdx.x;
  int lane = threadIdx.x;
  const float* xr = xs + (size_t)row*DIMC;
  float v[6];
  float s=0.f, s2=0.f;
  #pragma unroll
  for(int i=0;i<6;i++){ v[i]=xr[lane+i*64]; s+=v[i]; s2+=v[i]*v[i]; }
  #pragma unroll
  for(int m=32;m>=1;m>>=1){ s += __shfl_xor(s,m); s2 += __shfl_xor(s2,m); }
  float mean = s*(1.f/DIMC);
  float var  = s2*(1.f/DIMC)-mean*mean;
  float rstd = rsqrtf(var+1e-5f);
  if(lane==0){ meanr[row]=mean; rstdr[row]=rstd; }
  float xv1[6];
  #pragma unroll
  for(int i=0;i<6;i++){
    int c = lane+i*64;
    float nx = (v[i]-mean)*rstd;
    xv1[i] = nx*g1[c]+b1[c];
    xn2[(size_t)row*DIMC+c] = f2bfu(nx*g2[c]+b2[c]);
  }
  #pragma unroll
  for(int h=0;h<NHD;h++){
    float p=0.f;
    #pragma unroll
    for(int i=0;i<6;i++) p += xv1[i]*apw[h*DIMC+lane+i*64];
    #pragma unroll
    for(int m=32;m>=1;m>>=1) p += __shfl_xor(p,m);
    if(lane==0) scores[(size_t)row*NHD+h]=p+apb[h];
  }
}

// ---------------- softmax over L per (b,h), in-place ----------------
__global__ __launch_bounds__(256) void k_softmax_L(float* __restrict__ sc){
  int bh = blockIdx.x; int b = bh>>3, h = bh&7;
  int tid = threadIdx.x;
  __shared__ float red[8];
  const size_t base = (size_t)b*LSEQ*NHD + h;
  float mx = -1e30f;
  for(int l=tid;l<LSEQ;l+=256) mx = fmaxf(mx, sc[base + (size_t)l*NHD]);
  #pragma unroll
  for(int m=32;m>=1;m>>=1) mx = fmaxf(mx, __shfl_xor(mx,m));
  if((tid&63)==0) red[tid>>6]=mx;
  __syncthreads();
  mx = fmaxf(fmaxf(red[0],red[1]),fmaxf(red[2],red[3]));
  float sum=0.f;
  for(int l=tid;l<LSEQ;l+=256) sum += __expf(sc[base+(size_t)l*NHD]-mx);
  #pragma unroll
  for(int m=32;m>=1;m>>=1) sum += __shfl_xor(sum,m);
  if((tid&63)==0) red[4+(tid>>6)]=sum;
  __syncthreads();
  float inv = 1.f/(red[4]+red[5]+red[6]+red[7]);
  for(int l=tid;l<LSEQ;l+=256){
    size_t idx = base+(size_t)l*NHD;
    sc[idx] = __expf(sc[idx]-mx)*inv;
  }
}

__global__ void k_wpool(const float* __restrict__ attn, float* __restrict__ w){
  int i = blockIdx.x*256+threadIdx.x;
  if(i<MROWS){
    const float* a = attn+(size_t)i*NHD;
    float s=0.f;
    #pragma unroll
    for(int h=0;h<NHD;h++) s+=a[h];
    w[i]=s*0.125f;
  }
}

__global__ void k_zero(float* __restrict__ p, int n){
  int i=blockIdx.x*256+threadIdx.x; if(i<n)p[i]=0.f;
}

// gc[b,c] = sum_l w[b,l]*xn1[b,l,c]  (xn1 recomputed from XS + mean/rstd)
__global__ __launch_bounds__(384) void k_gc(const float* __restrict__ w,
    const float* __restrict__ xs, const float* __restrict__ meanr,
    const float* __restrict__ rstdr, const float* __restrict__ g1,
    const float* __restrict__ b1, float* __restrict__ gc){
  int b = blockIdx.x; int chunk = blockIdx.y; int c = threadIdx.x;
  int l0 = chunk*192;
  float acc=0.f, accw=0.f;
  for(int l=0;l<192;l++){
    int row = b*LSEQ + l0+l;
    float ww = w[row];
    acc  += ww*(xs[(size_t)row*DIMC+c]-meanr[row])*rstdr[row];
    accw += ww;
  }
  atomicAdd(&gc[b*DIMC+c], acc*g1[c]+accw*b1[c]);
}

__global__ __launch_bounds__(64) void k_mod1(const float* __restrict__ gc,
    const float* __restrict__ w1, const float* __restrict__ b1, float* __restrict__ h){
  int b = blockIdx.x; int n = blockIdx.y*64+threadIdx.x;
  const float* g = gc + b*DIMC;
  const float* wr = w1 + (size_t)n*DIMC;
  float acc=0.f;
  for(int k=0;k<DIMC;k++) acc += g[k]*wr[k];
  h[b*768+n] = silu_(acc+b1[n]);
}
__global__ __launch_bounds__(64) void k_mod2(const float* __restrict__ h,
    const float* __restrict__ w2, const float* __restrict__ b2, float* __restrict__ mod){
  int b = blockIdx.x; int n = blockIdx.y*64+threadIdx.x;
  const float* hh = h + b*768;
  const float* wr = w2 + (size_t)n*768;
  float acc=0.f;
  for(int k=0;k<768;k++) acc += hh[k]*wr[k];
  mod[b*DIMC+n] = acc+b2[n];
}

// =====================  bf16 MFMA GEMM (2-phase prefetch, dbuf LDS)  ==========
// out = epi(A @ W^T + bias).  A:(M,K) bf16 row-major, W:(N,K) bf16 row-major.
// Tile 128x128, BK=32, 256 threads = 4 waves (2x2 of 64x64).
// EPI: 0 bf16 store, 1 gelu->bf16, 2 f32: out += v*(1+aux[b,col]) in place,
//      3 final: d_out[(b*C+col)*L+t]=aux[row,col]+v (float4),
//      4 f32 store col<N guard, 5 split bf16: col<768 -> outp else outp2.
template<int EPI>
__global__ __launch_bounds__(256,2) void k_mgemm(
    const u16* __restrict__ A, const u16* __restrict__ W,
    const float* __restrict__ bias, void* __restrict__ outp,
    int K, int N, const float* __restrict__ aux, void* __restrict__ outp2)
{
  __shared__ u16 lA[2][4096];   // [buf][kc:4][row:128][8]  (8 KB each)
  __shared__ u16 lB[2][4096];
  int tid = threadIdx.x;
  int m0 = blockIdx.x*128, n0 = blockIdx.y*128;
  int wid = tid>>6, lane = tid&63;
  int wr = wid>>1, wc = wid&1;
  int lrow = lane&15, lk = lane>>4;
  f32x4 acc[4][4];
  #pragma unroll
  for(int i=0;i<4;i++)
    #pragma unroll
    for(int j=0;j<4;j++){ acc[i][j][0]=0.f; acc[i][j][1]=0.f; acc[i][j][2]=0.f; acc[i][j][3]=0.f; }

  // staging map: flat = q*256 + tid; kc = flat>>7 (0..3), row = flat&127.
  int r0 = tid & 127, k0 = tid >> 7;
  const u16* Ag0 = A + (size_t)(m0+r0)*K + k0*8;
  const u16* Ag1 = A + (size_t)(m0+r0)*K + (k0+2)*8;
  const u16* Bg0 = W + (size_t)(n0+r0)*K + k0*8;
  const u16* Bg1 = W + (size_t)(n0+r0)*K + (k0+2)*8;

  // prologue: stage tile 0 into buf 0
  gl_lds16(Ag0, &lA[0][tid*8]);
  gl_lds16(Ag1, &lA[0][2048+tid*8]);
  gl_lds16(Bg0, &lB[0][tid*8]);
  gl_lds16(Bg1, &lB[0][2048+tid*8]);
  __syncthreads();

  int cur = 0;
  for(int kb=0; kb<K; kb+=32){
    // issue next-tile prefetch before compute (latency overlaps MFMA+ds_read)
    if(kb+32 < K){
      int nb = cur^1;
      gl_lds16(Ag0 + kb+32, &lA[nb][tid*8]);
      gl_lds16(Ag1 + kb+32, &lA[nb][2048+tid*8]);
      gl_lds16(Bg0 + kb+32, &lB[nb][tid*8]);
      gl_lds16(Bg1 + kb+32, &lB[nb][2048+tid*8]);
    }
    bf16x8 af[4], bfr[4];
    #pragma unroll
    for(int i=0;i<4;i++){
      af[i]  = *reinterpret_cast<const bf16x8*>(&lA[cur][(lk*128 + wr*64 + i*16 + lrow)*8]);
      bfr[i] = *reinterpret_cast<const bf16x8*>(&lB[cur][(lk*128 + wc*64 + i*16 + lrow)*8]);
    }
    #pragma unroll
    for(int i=0;i<4;i++)
      #pragma unroll
      for(int j=0;j<4;j++)
        acc[i][j] = __builtin_amdgcn_mfma_f32_16x16x32_bf16(af[i], bfr[j], acc[i][j], 0,0,0);
    __syncthreads();   // drains prefetch (vmcnt) + all reads of cur done
    cur ^= 1;
  }

  #pragma unroll
  for(int i=0;i<4;i++){
    int row = m0 + wr*64 + i*16 + lk*4;
    #pragma unroll
    for(int j=0;j<4;j++){
      int col = n0 + wc*64 + j*16 + lrow;
      float bc = bias ? bias[col] : 0.f;
      f32x4 v = acc[i][j];
      if(EPI==0){
        u16* o = (u16*)outp;
        #pragma unroll
        for(int r=0;r<4;r++) o[(size_t)(row+r)*N + col] = f2bfu(v[r]+bc);
      } else if(EPI==1){
        u16* o = (u16*)outp;
        #pragma unroll
        for(int r=0;r<4;r++) o[(size_t)(row+r)*N + col] = f2bfu(gelu_(v[r]+bc));
      } else if(EPI==2){
        float* o = (float*)outp;
        int bi = row/LSEQ;
        float sc = 1.f + aux[bi*DIMC + col];
        #pragma unroll
        for(int r=0;r<4;r++) o[(size_t)(row+r)*DIMC + col] += (v[r]+bc)*sc;
      } else if(EPI==3){
        float* o = (float*)outp;
        int bi = row/LSEQ, t = row - bi*LSEQ;
        float4 s;
        s.x = aux[(size_t)(row+0)*DIMC+col] + v[0] + bc;
        s.y = aux[(size_t)(row+1)*DIMC+col] + v[1] + bc;
        s.z = aux[(size_t)(row+2)*DIMC+col] + v[2] + bc;
        s.w = aux[(size_t)(row+3)*DIMC+col] + v[3] + bc;
        *reinterpret_cast<float4*>(&o[((size_t)(bi*DIMC+col))*LSEQ + t]) = s;
      } else if(EPI==4){
        float* o = (float*)outp;
        if(col < N){
          #pragma unroll
          for(int r=0;r<4;r++) o[(size_t)(row+r)*N + col] = v[r]+bc;
        }
      } else { // EPI==5: split into two (M,768) bf16 outputs
        u16* o = (col < 768) ? (u16*)outp : (u16*)outp2;
        int cc = (col < 768) ? col : col - 768;
        #pragma unroll
        for(int r=0;r<4;r++) o[(size_t)(row+r)*768 + cc] = f2bfu(v[r]+bc);
      }
    }
  }
}

// ------- causal depthwise conv K=4 + silu, 8 channels/thread (bf16 in/out) -------
__global__ void k_conv(const u16* __restrict__ xm, const float* __restrict__ cw,
                       const float* __restrict__ cb, u16* __restrict__ u){
  int idx = blockIdx.x*256+threadIdx.x;
  if(idx >= MROWS*(DINN/8)) return;
  int j = idx % (DINN/8); int r = idx / (DINN/8);
  int t = r % LSEQ; int d0 = j*8;
  float4 w4_[8];
  #pragma unroll
  for(int e=0;e<8;e++) w4_[e] = reinterpret_cast<const float4*>(cw)[d0+e];
  float acc[8];
  #pragma unroll
  for(int e=0;e<8;e++) acc[e]=cb[d0+e];
  #pragma unroll
  for(int k=0;k<4;k++){
    int tt=t+k-3;
    if(tt>=0){
      uint4 v = *reinterpret_cast<const uint4*>(&xm[(size_t)(r+k-3)*DINN + d0]);
      unsigned vv[4]={v.x,v.y,v.z,v.w};
      #pragma unroll
      for(int e=0;e<8;e++){
        u16 raw = (e&1)? (u16)(vv[e>>1]>>16) : (u16)(vv[e>>1]&0xffffu);
        float wk = (k==0)? w4_[e].x : (k==1)? w4_[e].y : (k==2)? w4_[e].z : w4_[e].w;
        acc[e] += bfu2f(raw)*wk;
      }
    }
  }
  u16 outv[8];
  #pragma unroll
  for(int e=0;e<8;e++) outv[e]=f2bfu(silu_(acc[e]));
  *reinterpret_cast<uint4*>(&u[(size_t)r*DINN+d0]) = *reinterpret_cast<const uint4*>(outv);
}

// ---------------- small-K GEMM for delta (K=24) + softplus, bf16 out ----------------
__global__ __launch_bounds__(256) void k_dtgemm(const float* __restrict__ DBC,
    const float* __restrict__ dtw, const float* __restrict__ dtb,
    u16* __restrict__ delta){
  __shared__ float As[64][24];
  __shared__ float Ws[64][24];
  int tid = threadIdx.x;
  int m0 = blockIdx.x*64, n0 = blockIdx.y*64;
  for(int j=tid;j<64*24;j+=256){
    int rr=j/24, kk=j-rr*24;
    As[rr][kk]=DBC[(size_t)(m0+rr)*56+kk];
    Ws[rr][kk]=dtw[(size_t)(n0+rr)*24+kk];
  }
  __syncthreads();
  int tx=tid&15, ty=tid>>4;
  float acc[4][4]={};
  for(int k=0;k<24;k++){
    float a[4],w[4];
    #pragma unroll
    for(int i=0;i<4;i++){a[i]=As[ty*4+i][k]; w[i]=Ws[tx*4+i][k];}
    #pragma unroll
    for(int i=0;i<4;i++)
      #pragma unroll
      for(int j=0;j<4;j++) acc[i][j]+=a[i]*w[j];
  }
  #pragma unroll
  for(int i=0;i<4;i++){
    int row=m0+ty*4+i;
    #pragma unroll
    for(int j=0;j<4;j++){
      int col=n0+tx*4+j;
      delta[(size_t)row*DINN+col]=f2bfu(softplus_(acc[i][j]+dtb[col]));
    }
  }
}

// ============ chunked selective scan, d-per-thread ============
// A-structure fast path: if A[n] == (n+1)*A[0] (true for A_log=log(arange)),
// dA[n] = e^(n+1) with e = exp2(dt*A[0]*log2e): 1 exp + 16 muls per step.
// Generic fallback otherwise (checked per-thread at 1e-4 rel tol).
__global__ __launch_bounds__(256) void k_scan1(
  const u16* __restrict__ dt_, const u16* __restrict__ u_,
  const float* __restrict__ dbc, const float* __restrict__ alog,
  float* __restrict__ ssum, float* __restrict__ hloc)
{
  __shared__ float Bsh[TCH][16];
  int bid = blockIdx.x;
  int b = bid/(NCH*3); int rem = bid%(NCH*3); int ch = rem/3; int dblk = rem%3;
  int tid = threadIdx.x; int d = dblk*256 + tid;
  size_t rbase = (size_t)b*LSEQ + (size_t)ch*TCH;
  for(int j=tid; j<TCH*16; j+=256){
    int row=j>>4, n=j&15;
    Bsh[row][n] = dbc[(rbase+row)*56 + DTRK + n];
  }
  float Acl2[16];
  float a0 = -__expf(alog[(size_t)d*16])*L2E;
  bool fast = true;
  #pragma unroll
  for(int n=0;n<16;n++){
    Acl2[n] = -__expf(alog[(size_t)d*16+n])*L2E;
    float tgt = (float)(n+1)*a0;
    fast = fast && (fabsf(Acl2[n]-tgt) <= 1e-4f*fabsf(tgt));
  }
  float h[16];
  #pragma unroll
  for(int n=0;n<16;n++) h[n]=0.f;
  float S=0.f;
  const u16* dtp = dt_ + rbase*DINN + d;
  const u16* up  = u_  + rbase*DINN + d;
  __syncthreads();
  if(fast){
    for(int t=0;t<TCH;t++){
      float dt = bfu2f(dtp[(size_t)t*DINN]);
      float uv = bfu2f(up[(size_t)t*DINN]);
      float G = dt*uv;
      S += dt;
      float e = exp2f(dt*a0), w = e;
      const float4* b4 = (const float4*)Bsh[t];
      float4 B0=b4[0],B1=b4[1],B2=b4[2],B3=b4[3];
      float Bv[16]={B0.x,B0.y,B0.z,B0.w,B1.x,B1.y,B1.z,B1.w,
                    B2.x,B2.y,B2.z,B2.w,B3.x,B3.y,B3.z,B3.w};
      #pragma unroll
      for(int n=0;n<16;n++){ h[n] = h[n]*w + G*Bv[n]; w *= e; }
    }
  } else {
    for(int t=0;t<TCH;t++){
      float dt = bfu2f(dtp[(size_t)t*DINN]);
      float uv = bfu2f(up[(size_t)t*DINN]);
      float G = dt*uv;
      S += dt;
      const float4* b4 = (const float4*)Bsh[t];
      float4 B0=b4[0],B1=b4[1],B2=b4[2],B3=b4[3];
      float Bv[16]={B0.x,B0.y,B0.z,B0.w,B1.x,B1.y,B1.z,B1.w,
                    B2.x,B2.y,B2.z,B2.w,B3.x,B3.y,B3.z,B3.w};
      #pragma unroll
      for(int n=0;n<16;n++) h[n] = h[n]*exp2f(dt*Acl2[n]) + G*Bv[n];
    }
  }
  ssum[((size_t)b*NCH+ch)*DINN + d] = S;
  float* hp = hloc + (((size_t)b*NCH+ch)*DINN + d)*16;
  #pragma unroll
  for(int n=0;n<16;n++) hp[n] = h[n];
}

// pass 2: sequential combine over chunks; hl becomes h_in per chunk.
__global__ __launch_bounds__(256) void k_scan2(
  const float* __restrict__ ssum, const float* __restrict__ alog,
  float* __restrict__ hl)
{
  int gid = blockIdx.x*256+threadIdx.x;   // B*DINN*16
  int n = gid & 15; int d = (gid>>4)%DINN; int b = gid/(DINN*NSTATE);
  float Acl2 = -__expf(alog[(size_t)d*16+n])*L2E;
  float hin=0.f;
  for(int ch=0; ch<NCH; ch++){
    size_t sidx = ((size_t)b*NCH+ch)*DINN + d;
    size_t idx  = sidx*16 + n;
    float a = exp2f(ssum[sidx]*Acl2);
    float hold = hl[idx];
    hl[idx] = hin;
    hin = a*hin + hold;
  }
}

// pass 3: replay chunk from h_in, write y=(h.C + u*Dp)*silu(z) over u (in place).
__global__ __launch_bounds__(256) void k_scan3(
  const u16* __restrict__ dt_, u16* uy, const u16* __restrict__ z_,
  const float* __restrict__ dbc, const float* __restrict__ alog,
  const float* __restrict__ Dp, const float* __restrict__ hin)
{
  __shared__ float BC[TCH][32];
  int bid = blockIdx.x;
  int b = bid/(NCH*3); int rem = bid%(NCH*3); int ch = rem/3; int dblk = rem%3;
  int tid = threadIdx.x; int d = dblk*256 + tid;
  size_t rbase = (size_t)b*LSEQ + (size_t)ch*TCH;
  for(int j=tid; j<TCH*32; j+=256){
    int row=j>>5, c=j&31;
    BC[row][c] = dbc[(rbase+row)*56 + DTRK + c];
  }
  float Acl2[16], h[16];
  const float* hp = hin + (((size_t)b*NCH+ch)*DINN + d)*16;
  float a0 = -__expf(alog[(size_t)d*16])*L2E;
  bool fast = true;
  #pragma unroll
  for(int n=0;n<16;n++){
    Acl2[n] = -__expf(alog[(size_t)d*16+n])*L2E;
    float tgt = (float)(n+1)*a0;
    fast = fast && (fabsf(Acl2[n]-tgt) <= 1e-4f*fabsf(tgt));
    h[n] = hp[n];
  }
  float Dv = Dp[d];
  const u16* dtp = dt_ + rbase*DINN + d;
  u16*       uyp = uy  + rbase*DINN + d;
  const u16* zp  = z_  + rbase*DINN + d;
  __syncthreads();
  if(fast){
    for(int t=0;t<TCH;t++){
      float dt = bfu2f(dtp[(size_t)t*DINN]);
      float uv = bfu2f(uyp[(size_t)t*DINN]);
      float zv = bfu2f(zp[(size_t)t*DINN]);
      float G = dt*uv;
      float e = exp2f(dt*a0), w = e;
      const float4* bc4 = (const float4*)BC[t];
      float4 B0=bc4[0],B1=bc4[1],B2=bc4[2],B3=bc4[3];
      float4 C0=bc4[4],C1=bc4[5],C2=bc4[6],C3=bc4[7];
      float Bv[16]={B0.x,B0.y,B0.z,B0.w,B1.x,B1.y,B1.z,B1.w,
                    B2.x,B2.y,B2.z,B2.w,B3.x,B3.y,B3.z,B3.w};
      float Cv[16]={C0.x,C0.y,C0.z,C0.w,C1.x,C1.y,C1.z,C1.w,
                    C2.x,C2.y,C2.z,C2.w,C3.x,C3.y,C3.z,C3.w};
      float y0=0.f,y1=0.f,y2=0.f,y3=0.f;
      #pragma unroll
      for(int n=0;n<16;n++){
        h[n] = h[n]*w + G*Bv[n];
        w *= e;
        if((n&3)==0) y0 += h[n]*Cv[n];
        else if((n&3)==1) y1 += h[n]*Cv[n];
        else if((n&3)==2) y2 += h[n]*Cv[n];
        else y3 += h[n]*Cv[n];
      }
      float y = (y0+y1)+(y2+y3);
      uyp[(size_t)t*DINN] = f2bfu((y + uv*Dv)*silu_(zv));
    }
  } else {
    for(int t=0;t<TCH;t++){
      float dt = bfu2f(dtp[(size_t)t*DINN]);
      float uv = bfu2f(uyp[(size_t)t*DINN]);
      float zv = bfu2f(zp[(size_t)t*DINN]);
      float G = dt*uv;
      const float4* bc4 = (const float4*)BC[t];
      float4 B0=bc4[0],B1=bc4[1],B2=bc4[2],B3=bc4[3];
      float4 C0=bc4[4],C1=bc4[5],C2=bc4[6],C3=bc4[7];
      float Bv[16]={B0.x,B0.y,B0.z,B0.w,B1.x,B1.y,B1.z,B1.w,
                    B2.x,B2.y,B2.z,B2.w,B3.x,B3.y,B3.z,B3.w};
      float Cv[16]={C0.x,C0.y,C0.z,C0.w,C1.x,C1.y,C1.z,C1.w,
                    C2.x,C2.y,C2.z,C2.w,C3.x,C3.y,C3.z,C3.w};
      float y0=0.f,y1=0.f,y2=0.f,y3=0.f;
      #pragma unroll
      for(int n=0;n<16;n++){
        h[n] = h[n]*exp2f(dt*Acl2[n]) + G*Bv[n];
        if((n&3)==0) y0 += h[n]*Cv[n];
        else if((n&3)==1) y1 += h[n]*Cv[n];
        else if((n&3)==2) y2 += h[n]*Cv[n];
        else y3 += h[n]*Cv[n];
      }
      float y = (y0+y1)+(y2+y3);
      uyp[(size_t)t*DINN] = f2bfu((y + uv*Dv)*silu_(zv));
    }
  }
}

// ---------------- LN3, bf16 out ----------------
__global__ __launch_bounds__(64) void k_ln3(const float* __restrict__ xin,
    const float* __restrict__ g, const float* __restrict__ bb, u16* __restrict__ xout){
  int row = blockIdx.x;
  int lane = threadIdx.x;
  const float* xr = xin + (size_t)row*DIMC;
  float v[6];
  float s=0.f, s2=0.f;
  #pragma unroll
  for(int i=0;i<6;i++){ v[i]=xr[lane+i*64]; s+=v[i]; s2+=v[i]*v[i]; }
  #pragma unroll
  for(int m=32;m>=1;m>>=1){ s += __shfl_xor(s,m); s2 += __shfl_xor(s2,m); }
  float mean = s*(1.f/DIMC);
  float var  = s2*(1.f/DIMC)-mean*mean;
  float rstd = rsqrtf(var+1e-5f);
  #pragma unroll
  for(int i=0;i<6;i++){
    int c = lane+i*64;
    xout[(size_t)row*DIMC+c] = f2bfu((v[i]-mean)*rstd*g[c]+bb[c]);
  }
}

extern "C" void kernel_launch(void* const* d_in, const int* in_sizes, int n_in,
                              void* d_out, int out_size, void* d_ws, size_t ws_size,
                              hipStream_t stream)
{
  const float* x     = (const float*)d_in[0];
  const float* n1g   = (const float*)d_in[1];
  const float* n1b   = (const float*)d_in[2];
  const float* apw   = (const float*)d_in[3];
  const float* apb   = (const float*)d_in[4];
  const float* n2g   = (const float*)d_in[5];
  const float* n2b   = (const float*)d_in[6];
  const float* inw   = (const float*)d_in[7];
  const float* inb   = (const float*)d_in[8];
  const float* convw = (const float*)d_in[9];
  const float* convb = (const float*)d_in[10];
  const float* xpw   = (const float*)d_in[11];
  const float* dtw   = (const float*)d_in[12];
  const float* dtb   = (const float*)d_in[13];
  const float* Alog  = (const float*)d_in[14];
  const float* Dp    = (const float*)d_in[15];
  const float* outw  = (const float*)d_in[16];
  const float* outb  = (const float*)d_in[17];
  const float* modw1 = (const float*)d_in[18];
  const float* modb1 = (const float*)d_in[19];
  const float* modw2 = (const float*)d_in[20];
  const float* modb2 = (const float*)d_in[21];
  const float* n3g   = (const float*)d_in[22];
  const float* n3b   = (const float*)d_in[23];
  const float* fc1w  = (const float*)d_in[24];
  const float* fc1b  = (const float*)d_in[25];
  const float* fc2w  = (const float*)d_in[26];
  const float* fc2b  = (const float*)d_in[27];

  // ---- workspace layout (f32 slots), total 30,640,128 f = 122.6 MB ----
  float* ws = (float*)d_ws;
  float* XS    = ws;                       // 7,077,888 f
  float* R1    = ws + 7077888;             // 14,155,776 f multi-use region:
  //  phase A: XMb bf16 (M*768) in f[0..7.08M)
  //  phase B: DTb bf16 over XMb; SSUM f[7.08M..7.47M); HL f[7.47M..13.77M)
  //  phase C: F1b bf16 (M*1536) = full region
  u16*   XMb   = (u16*)R1;
  u16*   DTb   = (u16*)R1;
  float* SSUM  = R1 + 7077888;             // 393,216 f
  float* HL    = R1 + 7471104;             // 6,291,456 f
  u16*   F1b   = (u16*)R1;
  u16*   Zb    = (u16*)(ws + 21233664);    // 14,155,776 u16 (= 7,077,888 f)
  float* DBC   = ws + 28311552;            // 1,032,192 f
  float* WB    = ws + 29343744;            // bf16 weights, 1,081,344 f slots
  u16*   inw_b   = (u16*)WB;                     // 589,824 sh
  u16*   xpw_pad = inw_b + 589824;               // 98,304 sh (128x768, rows 56+ zero)
  u16*   outw_b  = xpw_pad + 98304;              // 294,912 sh
  u16*   fc1w_b  = outw_b + 294912;              // 589,824 sh
  u16*   fc2w_b  = fc1w_b + 589824;              // 589,824 sh
  float* SCORES= ws + 30425088;            // 147,456 f
  float* WPOOL = ws + 30572544;            // 18,432
  float* MEANR = ws + 30590976;            // 18,432
  float* RSTDR = ws + 30609408;            // 18,432
  float* GC    = ws + 30627840;            // 3,072
  float* MODH  = ws + 30630912;            // 6,144
  float* MOD   = ws + 30637056;            // 3,072
  (void)ws_size; (void)n_in; (void)in_sizes; (void)out_size;

  // d_out as scratch: XN2b bf16 -> Ub bf16 -> Y bf16 (in-place over Ub) -> Hb bf16
  u16* XN2b = (u16*)d_out;
  u16* Ub   = (u16*)d_out;
  u16* Hb   = (u16*)d_out;

  // weight conversion
  k_cvt<<<(589824+255)/256, 256, 0, stream>>>(inw,  inw_b,  589824);
  k_cvtpad<<<(98304+255)/256, 256, 0, stream>>>(xpw, xpw_pad, 56*768, 128*768);
  k_cvt<<<(294912+255)/256, 256, 0, stream>>>(outw, outw_b, 294912);
  k_cvt<<<(589824+255)/256, 256, 0, stream>>>(fc1w, fc1w_b, 589824);
  k_cvt<<<(589824+255)/256, 256, 0, stream>>>(fc2w, fc2w_b, 589824);

  k_transpose<<<dim3(72,12,8), dim3(32,8), 0, stream>>>(x, XS);
  k_lnstats<<<MROWS, 64, 0, stream>>>(XS, n1g,n1b,n2g,n2b, apw,apb, MEANR, RSTDR, XN2b, SCORES);
  k_softmax_L<<<BB*NHD, 256, 0, stream>>>(SCORES);
  k_wpool<<<(MROWS+255)/256, 256, 0, stream>>>(SCORES, WPOOL);
  k_zero<<<(BB*DIMC+255)/256, 256, 0, stream>>>(GC, BB*DIMC);
  k_gc<<<dim3(BB,12), 384, 0, stream>>>(WPOOL, XS, MEANR, RSTDR, n1g, n1b, GC);
  k_mod1<<<dim3(BB,12), 64, 0, stream>>>(GC, modw1, modb1, MODH);
  k_mod2<<<dim3(BB,6), 64, 0, stream>>>(MODH, modw2, modb2, MOD);

  // in_proj fused: [XMb | Zb] = XN2 @ inw^T + inb   (K=384, N=1536, split store)
  k_mgemm<5><<<dim3(144,12), 256, 0, stream>>>(XN2b, inw_b, inb, XMb, 384, 1536, nullptr, Zb);
  // conv + silu -> Ub (bf16, in d_out; XN2b dead)
  k_conv<<<(MROWS*(DINN/8)+255)/256, 256, 0, stream>>>(XMb, convw, convb, Ub);
  // dbc = u @ xp_w^T (K=768, N=56; W padded to 128 rows)
  k_mgemm<4><<<dim3(144,1), 256, 0, stream>>>(Ub, xpw_pad, nullptr, DBC, 768, 56, nullptr, nullptr);
  // delta = softplus(dbc[:, :24] @ dt_w^T + dt_b) -> DTb (over dead XMb)
  k_dtgemm<<<dim3(288,12), 256, 0, stream>>>(DBC, dtw, dtb, DTb);
  // chunked scan (d-per-thread, A-structure fast path)
  k_scan1<<<BB*NCH*3, 256, 0, stream>>>(DTb, Ub, DBC, Alog, SSUM, HL);
  k_scan2<<<384, 256, 0, stream>>>(SSUM, Alog, HL);
  k_scan3<<<BB*NCH*3, 256, 0, stream>>>(DTb, Ub, Zb, DBC, Alog, Dp, HL);
  // XS += (y @ out_w^T + out_b) * (1 + mod)   (K=768, N=384); Y lives in Ub slot
  k_mgemm<2><<<dim3(144,3), 256, 0, stream>>>(Ub, outw_b, outb, XS, 768, 384, MOD, nullptr);
  // Hb = LN3(XS)  (bf16, into d_out; Y dead)
  k_ln3<<<MROWS, 64, 0, stream>>>(XS, n3g, n3b, Hb);
  // F1b = gelu(H @ fc1_w^T + fc1_b)   (K=384, N=1536; overlays R1)
  k_mgemm<1><<<dim3(144,12), 256, 0, stream>>>(Hb, fc1w_b, fc1b, F1b, 384, 1536, nullptr, nullptr);
  // d_out = transpose(XS + F1 @ fc2_w^T + fc2_b)   (K=1536, N=384)
  k_mgemm<3><<<dim3(144,3), 256, 0, stream>>>(F1b, fc2w_b, fc2b, d_out, 1536, 384, XS, nullptr);
}

// Round 6
// 535.768 us; speedup vs baseline: 4.5060x; 1.0665x over previous
//
#include <hip/hip_runtime.h>
#include <math.h>

#define DIMC 384
#define NHD 8
#define NSTATE 16
#define DINN 768
#define DTRK 24
#define BB 8
#define LSEQ 2304
#define MROWS (BB*LSEQ)   // 18432
#define NCH 64
#define TCH 36            // LSEQ / NCH
#define L2E 1.44269504f

typedef unsigned short u16;
typedef short bf16x8 __attribute__((ext_vector_type(8)));
typedef float f32x4 __attribute__((ext_vector_type(4)));

__device__ __forceinline__ float sigmoid_(float x){ return 1.f/(1.f+__expf(-x)); }
__device__ __forceinline__ float silu_(float x){ return x*sigmoid_(x); }
__device__ __forceinline__ float softplus_(float x){ return (x>20.f)?x:log1pf(__expf(x)); }
__device__ __forceinline__ float gelu_(float x){
  float x3=x*x*x;
  return 0.5f*x*(1.f+tanhf(0.7978845608028654f*(x+0.044715f*x3)));
}
__device__ __forceinline__ float bfu2f(u16 u){
  union{unsigned int i; float f;} c; c.i=((unsigned int)u)<<16; return c.f;
}
__device__ __forceinline__ u16 f2bfu(float f){
  union{float f; unsigned int i;} c; c.f=f;
  unsigned int r = c.i + 0x7FFFu + ((c.i>>16)&1u);
  return (u16)(r>>16);
}
// async global->LDS, 16B per lane; dest must be wave-uniform base + lane*16
__device__ __forceinline__ void gl_lds16(const u16* g, u16* l){
  __builtin_amdgcn_global_load_lds((__attribute__((address_space(1))) void*)g,
      (__attribute__((address_space(3))) void*)l, 16, 0, 0);
}

// ---------------- fused weight convert + GC zero ----------------
// segments (u16 elems): inw 589824 | xpw_pad 98304 (src 43008) | outw 294912 |
// fc1w 589824 | fc2w 589824 | dtw_pad 24576 (768x32, src 768x24) | GC zero 3072 (f32)
#define O1 589824
#define O2 688128
#define O3 983040
#define O4 1572864
#define O5 2162688
#define O6 2187264
#define OEND 2190336
__global__ void k_cvtall(const float* __restrict__ inw, const float* __restrict__ xpw,
    const float* __restrict__ outw, const float* __restrict__ fc1w,
    const float* __restrict__ fc2w, const float* __restrict__ dtw,
    u16* __restrict__ inw_b, u16* __restrict__ xpw_pad, u16* __restrict__ outw_b,
    u16* __restrict__ fc1w_b, u16* __restrict__ fc2w_b, u16* __restrict__ dtw_pad,
    float* __restrict__ gc){
  int i = blockIdx.x*256+threadIdx.x;
  if(i >= OEND) return;
  if(i < O1){ inw_b[i]=f2bfu(inw[i]); }
  else if(i < O2){ int j=i-O1; xpw_pad[j] = (j<43008)? f2bfu(xpw[j]) : (u16)0; }
  else if(i < O3){ int j=i-O2; outw_b[j]=f2bfu(outw[j]); }
  else if(i < O4){ int j=i-O3; fc1w_b[j]=f2bfu(fc1w[j]); }
  else if(i < O5){ int j=i-O4; fc2w_b[j]=f2bfu(fc2w[j]); }
  else if(i < O6){ int j=i-O5; int r=j>>5, c=j&31;
                   dtw_pad[j] = (c<DTRK)? f2bfu(dtw[r*DTRK+c]) : (u16)0; }
  else { gc[i-O6]=0.f; }
}

// ---------------- transpose (B,C,L) -> (B,L,C) ----------------
__global__ void k_transpose(const float* __restrict__ x, float* __restrict__ xs){
  __shared__ float tile[32][33];
  int b = blockIdx.z;
  int t0 = blockIdx.x*32, c0 = blockIdx.y*32;
  int tx = threadIdx.x, ty = threadIdx.y; // 32 x 8
  const float* xb = x + (size_t)b*DIMC*LSEQ;
  #pragma unroll
  for(int q=0;q<4;q++)
    tile[ty+q*8][tx] = xb[(size_t)(c0+ty+q*8)*LSEQ + t0+tx];
  __syncthreads();
  float* xsb = xs + (size_t)b*LSEQ*DIMC;
  #pragma unroll
  for(int q=0;q<4;q++)
    xsb[(size_t)(t0+ty+q*8)*DIMC + c0+tx] = tile[tx][ty+q*8];
}

// -------- LN stats + LN2 (bf16 out) + attention scores --------
__global__ __launch_bounds__(64) void k_lnstats(const float* __restrict__ xs,
   const float* __restrict__ g1,const float* __restrict__ b1,
   const float* __restrict__ g2,const float* __restrict__ b2,
   const float* __restrict__ apw,const float* __restrict__ apb,
   float* __restrict__ meanr, float* __restrict__ rstdr,
   u16* __restrict__ xn2, float* __restrict__ scores){
  int row = blockIdx.x;
  int lane = threadIdx.x;
  const float* xr = xs + (size_t)row*DIMC;
  float v[6];
  float s=0.f, s2=0.f;
  #pragma unroll
  for(int i=0;i<6;i++){ v[i]=xr[lane+i*64]; s+=v[i]; s2+=v[i]*v[i]; }
  #pragma unroll
  for(int m=32;m>=1;m>>=1){ s += __shfl_xor(s,m); s2 += __shfl_xor(s2,m); }
  float mean = s*(1.f/DIMC);
  float var  = s2*(1.f/DIMC)-mean*mean;
  float rstd = rsqrtf(var+1e-5f);
  if(lane==0){ meanr[row]=mean; rstdr[row]=rstd; }
  float xv1[6];
  #pragma unroll
  for(int i=0;i<6;i++){
    int c = lane+i*64;
    float nx = (v[i]-mean)*rstd;
    xv1[i] = nx*g1[c]+b1[c];
    xn2[(size_t)row*DIMC+c] = f2bfu(nx*g2[c]+b2[c]);
  }
  #pragma unroll
  for(int h=0;h<NHD;h++){
    float p=0.f;
    #pragma unroll
    for(int i=0;i<6;i++) p += xv1[i]*apw[h*DIMC+lane+i*64];
    #pragma unroll
    for(int m=32;m>=1;m>>=1) p += __shfl_xor(p,m);
    if(lane==0) scores[(size_t)row*NHD+h]=p+apb[h];
  }
}

// ---------------- softmax over L per (b,h), in-place ----------------
__global__ __launch_bounds__(256) void k_softmax_L(float* __restrict__ sc){
  int bh = blockIdx.x; int b = bh>>3, h = bh&7;
  int tid = threadIdx.x;
  __shared__ float red[8];
  const size_t base = (size_t)b*LSEQ*NHD + h;
  float mx = -1e30f;
  for(int l=tid;l<LSEQ;l+=256) mx = fmaxf(mx, sc[base + (size_t)l*NHD]);
  #pragma unroll
  for(int m=32;m>=1;m>>=1) mx = fmaxf(mx, __shfl_xor(mx,m));
  if((tid&63)==0) red[tid>>6]=mx;
  __syncthreads();
  mx = fmaxf(fmaxf(red[0],red[1]),fmaxf(red[2],red[3]));
  float sum=0.f;
  for(int l=tid;l<LSEQ;l+=256) sum += __expf(sc[base+(size_t)l*NHD]-mx);
  #pragma unroll
  for(int m=32;m>=1;m>>=1) sum += __shfl_xor(sum,m);
  if((tid&63)==0) red[4+(tid>>6)]=sum;
  __syncthreads();
  float inv = 1.f/(red[4]+red[5]+red[6]+red[7]);
  for(int l=tid;l<LSEQ;l+=256){
    size_t idx = base+(size_t)l*NHD;
    sc[idx] = __expf(sc[idx]-mx)*inv;
  }
}

__global__ void k_wpool(const float* __restrict__ attn, float* __restrict__ w){
  int i = blockIdx.x*256+threadIdx.x;
  if(i<MROWS){
    const float* a = attn+(size_t)i*NHD;
    float s=0.f;
    #pragma unroll
    for(int h=0;h<NHD;h++) s+=a[h];
    w[i]=s*0.125f;
  }
}

// gc[b,c] = sum_l w[b,l]*xn1[b,l,c]  (xn1 recomputed from XS + mean/rstd)
__global__ __launch_bounds__(384) void k_gc(const float* __restrict__ w,
    const float* __restrict__ xs, const float* __restrict__ meanr,
    const float* __restrict__ rstdr, const float* __restrict__ g1,
    const float* __restrict__ b1, float* __restrict__ gc){
  int b = blockIdx.x; int chunk = blockIdx.y; int c = threadIdx.x;
  int l0 = chunk*48;
  float acc=0.f, accw=0.f;
  for(int l=0;l<48;l++){
    int row = b*LSEQ + l0+l;
    float ww = w[row];
    acc  += ww*(xs[(size_t)row*DIMC+c]-meanr[row])*rstdr[row];
    accw += ww;
  }
  atomicAdd(&gc[b*DIMC+c], acc*g1[c]+accw*b1[c]);
}

__global__ __launch_bounds__(64) void k_mod1(const float* __restrict__ gc,
    const float* __restrict__ w1, const float* __restrict__ b1, float* __restrict__ h){
  int b = blockIdx.x; int n = blockIdx.y*64+threadIdx.x;
  const float* g = gc + b*DIMC;
  const float* wr = w1 + (size_t)n*DIMC;
  float acc=0.f;
  for(int k=0;k<DIMC;k++) acc += g[k]*wr[k];
  h[b*768+n] = silu_(acc+b1[n]);
}
__global__ __launch_bounds__(64) void k_mod2(const float* __restrict__ h,
    const float* __restrict__ w2, const float* __restrict__ b2, float* __restrict__ mod){
  int b = blockIdx.x; int n = blockIdx.y*64+threadIdx.x;
  const float* hh = h + b*768;
  const float* wr = w2 + (size_t)n*768;
  float acc=0.f;
  for(int k=0;k<768;k++) acc += hh[k]*wr[k];
  mod[b*DIMC+n] = acc+b2[n];
}

// =====================  bf16 MFMA GEMM (2-phase prefetch, dbuf LDS)  ==========
// out = epi(A @ W^T + bias).  A:(M,K) bf16 row-major, W:(N,K) bf16 row-major.
// Tile 128x128, BK=32, 256 threads = 4 waves (2x2 of 64x64).
// EPI: 0 bf16 store, 1 gelu->bf16, 2 f32: out += v*(1+aux[b,col]) in place,
//      3 final: d_out[(b*C+col)*L+t]=aux[row,col]+v (float4),
//      4 f32 store col<N guard, 5 split bf16: col<768 -> outp else outp2,
//      6 f32 col<56 -> outp (stride 56) + bf16 col<32 (pad>=24 zero) -> outp2 (stride 32),
//      7 softplus->bf16.
template<int EPI>
__global__ __launch_bounds__(256,2) void k_mgemm(
    const u16* __restrict__ A, const u16* __restrict__ W,
    const float* __restrict__ bias, void* __restrict__ outp,
    int K, int N, const float* __restrict__ aux, void* __restrict__ outp2)
{
  __shared__ u16 lA[2][4096];   // [buf][kc:4][row:128][8]  (8 KB each)
  __shared__ u16 lB[2][4096];
  int tid = threadIdx.x;
  int m0 = blockIdx.x*128, n0 = blockIdx.y*128;
  int wid = tid>>6, lane = tid&63;
  int wr = wid>>1, wc = wid&1;
  int lrow = lane&15, lk = lane>>4;
  f32x4 acc[4][4];
  #pragma unroll
  for(int i=0;i<4;i++)
    #pragma unroll
    for(int j=0;j<4;j++){ acc[i][j][0]=0.f; acc[i][j][1]=0.f; acc[i][j][2]=0.f; acc[i][j][3]=0.f; }

  // staging map: flat = q*256 + tid; kc = flat>>7 (0..3), row = flat&127.
  int r0 = tid & 127, k0 = tid >> 7;
  const u16* Ag0 = A + (size_t)(m0+r0)*K + k0*8;
  const u16* Ag1 = A + (size_t)(m0+r0)*K + (k0+2)*8;
  const u16* Bg0 = W + (size_t)(n0+r0)*K + k0*8;
  const u16* Bg1 = W + (size_t)(n0+r0)*K + (k0+2)*8;

  // prologue: stage tile 0 into buf 0
  gl_lds16(Ag0, &lA[0][tid*8]);
  gl_lds16(Ag1, &lA[0][2048+tid*8]);
  gl_lds16(Bg0, &lB[0][tid*8]);
  gl_lds16(Bg1, &lB[0][2048+tid*8]);
  __syncthreads();

  int cur = 0;
  for(int kb=0; kb<K; kb+=32){
    // issue next-tile prefetch before compute (latency overlaps MFMA+ds_read)
    if(kb+32 < K){
      int nb = cur^1;
      gl_lds16(Ag0 + kb+32, &lA[nb][tid*8]);
      gl_lds16(Ag1 + kb+32, &lA[nb][2048+tid*8]);
      gl_lds16(Bg0 + kb+32, &lB[nb][tid*8]);
      gl_lds16(Bg1 + kb+32, &lB[nb][2048+tid*8]);
    }
    bf16x8 af[4], bfr[4];
    #pragma unroll
    for(int i=0;i<4;i++){
      af[i]  = *reinterpret_cast<const bf16x8*>(&lA[cur][(lk*128 + wr*64 + i*16 + lrow)*8]);
      bfr[i] = *reinterpret_cast<const bf16x8*>(&lB[cur][(lk*128 + wc*64 + i*16 + lrow)*8]);
    }
    #pragma unroll
    for(int i=0;i<4;i++)
      #pragma unroll
      for(int j=0;j<4;j++)
        acc[i][j] = __builtin_amdgcn_mfma_f32_16x16x32_bf16(af[i], bfr[j], acc[i][j], 0,0,0);
    __syncthreads();   // drains prefetch (vmcnt) + all reads of cur done
    cur ^= 1;
  }

  #pragma unroll
  for(int i=0;i<4;i++){
    int row = m0 + wr*64 + i*16 + lk*4;
    #pragma unroll
    for(int j=0;j<4;j++){
      int col = n0 + wc*64 + j*16 + lrow;
      float bc = bias ? bias[col] : 0.f;
      f32x4 v = acc[i][j];
      if(EPI==0){
        u16* o = (u16*)outp;
        #pragma unroll
        for(int r=0;r<4;r++) o[(size_t)(row+r)*N + col] = f2bfu(v[r]+bc);
      } else if(EPI==1){
        u16* o = (u16*)outp;
        #pragma unroll
        for(int r=0;r<4;r++) o[(size_t)(row+r)*N + col] = f2bfu(gelu_(v[r]+bc));
      } else if(EPI==2){
        float* o = (float*)outp;
        int bi = row/LSEQ;
        float sc = 1.f + aux[bi*DIMC + col];
        #pragma unroll
        for(int r=0;r<4;r++) o[(size_t)(row+r)*DIMC + col] += (v[r]+bc)*sc;
      } else if(EPI==3){
        float* o = (float*)outp;
        int bi = row/LSEQ, t = row - bi*LSEQ;
        float4 s;
        s.x = aux[(size_t)(row+0)*DIMC+col] + v[0] + bc;
        s.y = aux[(size_t)(row+1)*DIMC+col] + v[1] + bc;
        s.z = aux[(size_t)(row+2)*DIMC+col] + v[2] + bc;
        s.w = aux[(size_t)(row+3)*DIMC+col] + v[3] + bc;
        *reinterpret_cast<float4*>(&o[((size_t)(bi*DIMC+col))*LSEQ + t]) = s;
      } else if(EPI==4){
        float* o = (float*)outp;
        if(col < N){
          #pragma unroll
          for(int r=0;r<4;r++) o[(size_t)(row+r)*N + col] = v[r]+bc;
        }
      } else if(EPI==5){ // split into two (M,768) bf16 outputs
        u16* o = (col < 768) ? (u16*)outp : (u16*)outp2;
        int cc = (col < 768) ? col : col - 768;
        #pragma unroll
        for(int r=0;r<4;r++) o[(size_t)(row+r)*768 + cc] = f2bfu(v[r]+bc);
      } else if(EPI==6){ // dbc f32 (col<56) + dt-input bf16 K-padded to 32
        float* o = (float*)outp;
        u16* o2 = (u16*)outp2;
        #pragma unroll
        for(int r=0;r<4;r++){
          float val = v[r];
          if(col < 56) o[(size_t)(row+r)*56 + col] = val;
          if(col < 32) o2[(size_t)(row+r)*32 + col] = (col<DTRK)? f2bfu(val) : (u16)0;
        }
      } else { // EPI==7: softplus -> bf16
        u16* o = (u16*)outp;
        #pragma unroll
        for(int r=0;r<4;r++) o[(size_t)(row+r)*N + col] = f2bfu(softplus_(v[r]+bc));
      }
    }
  }
}

// ------- causal depthwise conv K=4 + silu, 8 channels/thread (bf16 in/out) -------
__global__ void k_conv(const u16* __restrict__ xm, const float* __restrict__ cw,
                       const float* __restrict__ cb, u16* __restrict__ u){
  int idx = blockIdx.x*256+threadIdx.x;
  if(idx >= MROWS*(DINN/8)) return;
  int j = idx % (DINN/8); int r = idx / (DINN/8);
  int t = r % LSEQ; int d0 = j*8;
  float4 w4_[8];
  #pragma unroll
  for(int e=0;e<8;e++) w4_[e] = reinterpret_cast<const float4*>(cw)[d0+e];
  float acc[8];
  #pragma unroll
  for(int e=0;e<8;e++) acc[e]=cb[d0+e];
  #pragma unroll
  for(int k=0;k<4;k++){
    int tt=t+k-3;
    if(tt>=0){
      uint4 v = *reinterpret_cast<const uint4*>(&xm[(size_t)(r+k-3)*DINN + d0]);
      unsigned vv[4]={v.x,v.y,v.z,v.w};
      #pragma unroll
      for(int e=0;e<8;e++){
        u16 raw = (e&1)? (u16)(vv[e>>1]>>16) : (u16)(vv[e>>1]&0xffffu);
        float wk = (k==0)? w4_[e].x : (k==1)? w4_[e].y : (k==2)? w4_[e].z : w4_[e].w;
        acc[e] += bfu2f(raw)*wk;
      }
    }
  }
  u16 outv[8];
  #pragma unroll
  for(int e=0;e<8;e++) outv[e]=f2bfu(silu_(acc[e]));
  *reinterpret_cast<uint4*>(&u[(size_t)r*DINN+d0]) = *reinterpret_cast<const uint4*>(outv);
}

// ============ chunked selective scan, d-per-thread ============
// A-structure fast path: if A[n] == (n+1)*A[0] (true for A_log=log(arange)),
// dA[n] = e^(n+1) with e = exp2(dt*A[0]*log2e): 1 exp + 16 muls per step.
// Generic fallback otherwise (checked per-thread at 1e-4 rel tol).
__global__ __launch_bounds__(256) void k_scan1(
  const u16* __restrict__ dt_, const u16* __restrict__ u_,
  const float* __restrict__ dbc, const float* __restrict__ alog,
  float* __restrict__ ssum, float* __restrict__ hloc)
{
  __shared__ float Bsh[TCH][16];
  int bid = blockIdx.x;
  int b = bid/(NCH*3); int rem = bid%(NCH*3); int ch = rem/3; int dblk = rem%3;
  int tid = threadIdx.x; int d = dblk*256 + tid;
  size_t rbase = (size_t)b*LSEQ + (size_t)ch*TCH;
  for(int j=tid; j<TCH*16; j+=256){
    int row=j>>4, n=j&15;
    Bsh[row][n] = dbc[(rbase+row)*56 + DTRK + n];
  }
  float Acl2[16];
  float a0 = -__expf(alog[(size_t)d*16])*L2E;
  bool fast = true;
  #pragma unroll
  for(int n=0;n<16;n++){
    Acl2[n] = -__expf(alog[(size_t)d*16+n])*L2E;
    float tgt = (float)(n+1)*a0;
    fast = fast && (fabsf(Acl2[n]-tgt) <= 1e-4f*fabsf(tgt));
  }
  float h[16];
  #pragma unroll
  for(int n=0;n<16;n++) h[n]=0.f;
  float S=0.f;
  const u16* dtp = dt_ + rbase*DINN + d;
  const u16* up  = u_  + rbase*DINN + d;
  __syncthreads();
  if(fast){
    for(int t=0;t<TCH;t++){
      float dt = bfu2f(dtp[(size_t)t*DINN]);
      float uv = bfu2f(up[(size_t)t*DINN]);
      float G = dt*uv;
      S += dt;
      float e = exp2f(dt*a0), w = e;
      const float4* b4 = (const float4*)Bsh[t];
      float4 B0=b4[0],B1=b4[1],B2=b4[2],B3=b4[3];
      float Bv[16]={B0.x,B0.y,B0.z,B0.w,B1.x,B1.y,B1.z,B1.w,
                    B2.x,B2.y,B2.z,B2.w,B3.x,B3.y,B3.z,B3.w};
      #pragma unroll
      for(int n=0;n<16;n++){ h[n] = h[n]*w + G*Bv[n]; w *= e; }
    }
  } else {
    for(int t=0;t<TCH;t++){
      float dt = bfu2f(dtp[(size_t)t*DINN]);
      float uv = bfu2f(up[(size_t)t*DINN]);
      float G = dt*uv;
      S += dt;
      const float4* b4 = (const float4*)Bsh[t];
      float4 B0=b4[0],B1=b4[1],B2=b4[2],B3=b4[3];
      float Bv[16]={B0.x,B0.y,B0.z,B0.w,B1.x,B1.y,B1.z,B1.w,
                    B2.x,B2.y,B2.z,B2.w,B3.x,B3.y,B3.z,B3.w};
      #pragma unroll
      for(int n=0;n<16;n++) h[n] = h[n]*exp2f(dt*Acl2[n]) + G*Bv[n];
    }
  }
  ssum[((size_t)b*NCH+ch)*DINN + d] = S;
  float* hp = hloc + (((size_t)b*NCH+ch)*DINN + d)*16;
  #pragma unroll
  for(int n=0;n<16;n++) hp[n] = h[n];
}

// pass 2: sequential combine over chunks; hl becomes h_in per chunk.
__global__ __launch_bounds__(256) void k_scan2(
  const float* __restrict__ ssum, const float* __restrict__ alog,
  float* __restrict__ hl)
{
  int gid = blockIdx.x*256+threadIdx.x;   // B*DINN*16
  int n = gid & 15; int d = (gid>>4)%DINN; int b = gid/(DINN*NSTATE);
  float Acl2 = -__expf(alog[(size_t)d*16+n])*L2E;
  float hin=0.f;
  for(int ch=0; ch<NCH; ch++){
    size_t sidx = ((size_t)b*NCH+ch)*DINN + d;
    size_t idx  = sidx*16 + n;
    float a = exp2f(ssum[sidx]*Acl2);
    float hold = hl[idx];
    hl[idx] = hin;
    hin = a*hin + hold;
  }
}

// pass 3: replay chunk from h_in, write y=(h.C + u*Dp)*silu(z) over u (in place).
__global__ __launch_bounds__(256) void k_scan3(
  const u16* __restrict__ dt_, u16* uy, const u16* __restrict__ z_,
  const float* __restrict__ dbc, const float* __restrict__ alog,
  const float* __restrict__ Dp, const float* __restrict__ hin)
{
  __shared__ float BC[TCH][32];
  int bid = blockIdx.x;
  int b = bid/(NCH*3); int rem = bid%(NCH*3); int ch = rem/3; int dblk = rem%3;
  int tid = threadIdx.x; int d = dblk*256 + tid;
  size_t rbase = (size_t)b*LSEQ + (size_t)ch*TCH;
  for(int j=tid; j<TCH*32; j+=256){
    int row=j>>5, c=j&31;
    BC[row][c] = dbc[(rbase+row)*56 + DTRK + c];
  }
  float Acl2[16], h[16];
  const float* hp = hin + (((size_t)b*NCH+ch)*DINN + d)*16;
  float a0 = -__expf(alog[(size_t)d*16])*L2E;
  bool fast = true;
  #pragma unroll
  for(int n=0;n<16;n++){
    Acl2[n] = -__expf(alog[(size_t)d*16+n])*L2E;
    float tgt = (float)(n+1)*a0;
    fast = fast && (fabsf(Acl2[n]-tgt) <= 1e-4f*fabsf(tgt));
    h[n] = hp[n];
  }
  float Dv = Dp[d];
  const u16* dtp = dt_ + rbase*DINN + d;
  u16*       uyp = uy  + rbase*DINN + d;
  const u16* zp  = z_  + rbase*DINN + d;
  __syncthreads();
  if(fast){
    for(int t=0;t<TCH;t++){
      float dt = bfu2f(dtp[(size_t)t*DINN]);
      float uv = bfu2f(uyp[(size_t)t*DINN]);
      float zv = bfu2f(zp[(size_t)t*DINN]);
      float G = dt*uv;
      float e = exp2f(dt*a0), w = e;
      const float4* bc4 = (const float4*)BC[t];
      float4 B0=bc4[0],B1=bc4[1],B2=bc4[2],B3=bc4[3];
      float4 C0=bc4[4],C1=bc4[5],C2=bc4[6],C3=bc4[7];
      float Bv[16]={B0.x,B0.y,B0.z,B0.w,B1.x,B1.y,B1.z,B1.w,
                    B2.x,B2.y,B2.z,B2.w,B3.x,B3.y,B3.z,B3.w};
      float Cv[16]={C0.x,C0.y,C0.z,C0.w,C1.x,C1.y,C1.z,C1.w,
                    C2.x,C2.y,C2.z,C2.w,C3.x,C3.y,C3.z,C3.w};
      float y0=0.f,y1=0.f,y2=0.f,y3=0.f;
      #pragma unroll
      for(int n=0;n<16;n++){
        h[n] = h[n]*w + G*Bv[n];
        w *= e;
        if((n&3)==0) y0 += h[n]*Cv[n];
        else if((n&3)==1) y1 += h[n]*Cv[n];
        else if((n&3)==2) y2 += h[n]*Cv[n];
        else y3 += h[n]*Cv[n];
      }
      float y = (y0+y1)+(y2+y3);
      uyp[(size_t)t*DINN] = f2bfu((y + uv*Dv)*silu_(zv));
    }
  } else {
    for(int t=0;t<TCH;t++){
      float dt = bfu2f(dtp[(size_t)t*DINN]);
      float uv = bfu2f(uyp[(size_t)t*DINN]);
      float zv = bfu2f(zp[(size_t)t*DINN]);
      float G = dt*uv;
      const float4* bc4 = (const float4*)BC[t];
      float4 B0=bc4[0],B1=bc4[1],B2=bc4[2],B3=bc4[3];
      float4 C0=bc4[4],C1=bc4[5],C2=bc4[6],C3=bc4[7];
      float Bv[16]={B0.x,B0.y,B0.z,B0.w,B1.x,B1.y,B1.z,B1.w,
                    B2.x,B2.y,B2.z,B2.w,B3.x,B3.y,B3.z,B3.w};
      float Cv[16]={C0.x,C0.y,C0.z,C0.w,C1.x,C1.y,C1.z,C1.w,
                    C2.x,C2.y,C2.z,C2.w,C3.x,C3.y,C3.z,C3.w};
      float y0=0.f,y1=0.f,y2=0.f,y3=0.f;
      #pragma unroll
      for(int n=0;n<16;n++){
        h[n] = h[n]*exp2f(dt*Acl2[n]) + G*Bv[n];
        if((n&3)==0) y0 += h[n]*Cv[n];
        else if((n&3)==1) y1 += h[n]*Cv[n];
        else if((n&3)==2) y2 += h[n]*Cv[n];
        else y3 += h[n]*Cv[n];
      }
      float y = (y0+y1)+(y2+y3);
      uyp[(size_t)t*DINN] = f2bfu((y + uv*Dv)*silu_(zv));
    }
  }
}

// ---------------- LN3, bf16 out ----------------
__global__ __launch_bounds__(64) void k_ln3(const float* __restrict__ xin,
    const float* __restrict__ g, const float* __restrict__ bb, u16* __restrict__ xout){
  int row = blockIdx.x;
  int lane = threadIdx.x;
  const float* xr = xin + (size_t)row*DIMC;
  float v[6];
  float s=0.f, s2=0.f;
  #pragma unroll
  for(int i=0;i<6;i++){ v[i]=xr[lane+i*64]; s+=v[i]; s2+=v[i]*v[i]; }
  #pragma unroll
  for(int m=32;m>=1;m>>=1){ s += __shfl_xor(s,m); s2 += __shfl_xor(s2,m); }
  float mean = s*(1.f/DIMC);
  float var  = s2*(1.f/DIMC)-mean*mean;
  float rstd = rsqrtf(var+1e-5f);
  #pragma unroll
  for(int i=0;i<6;i++){
    int c = lane+i*64;
    xout[(size_t)row*DIMC+c] = f2bfu((v[i]-mean)*rstd*g[c]+bb[c]);
  }
}

extern "C" void kernel_launch(void* const* d_in, const int* in_sizes, int n_in,
                              void* d_out, int out_size, void* d_ws, size_t ws_size,
                              hipStream_t stream)
{
  const float* x     = (const float*)d_in[0];
  const float* n1g   = (const float*)d_in[1];
  const float* n1b   = (const float*)d_in[2];
  const float* apw   = (const float*)d_in[3];
  const float* apb   = (const float*)d_in[4];
  const float* n2g   = (const float*)d_in[5];
  const float* n2b   = (const float*)d_in[6];
  const float* inw   = (const float*)d_in[7];
  const float* inb   = (const float*)d_in[8];
  const float* convw = (const float*)d_in[9];
  const float* convb = (const float*)d_in[10];
  const float* xpw   = (const float*)d_in[11];
  const float* dtw   = (const float*)d_in[12];
  const float* dtb   = (const float*)d_in[13];
  const float* Alog  = (const float*)d_in[14];
  const float* Dp    = (const float*)d_in[15];
  const float* outw  = (const float*)d_in[16];
  const float* outb  = (const float*)d_in[17];
  const float* modw1 = (const float*)d_in[18];
  const float* modb1 = (const float*)d_in[19];
  const float* modw2 = (const float*)d_in[20];
  const float* modb2 = (const float*)d_in[21];
  const float* n3g   = (const float*)d_in[22];
  const float* n3b   = (const float*)d_in[23];
  const float* fc1w  = (const float*)d_in[24];
  const float* fc1b  = (const float*)d_in[25];
  const float* fc2w  = (const float*)d_in[26];
  const float* fc2b  = (const float*)d_in[27];

  // ---- workspace layout (f32 slots), total ~30.95M f = 123.8 MB ----
  float* ws = (float*)d_ws;
  float* XS    = ws;                       // 7,077,888 f
  float* R1    = ws + 7077888;             // 14,155,776 f multi-use region:
  //  phase A: XMb bf16 (M*768) in f[0..7.08M)
  //  phase B: DTb bf16 over XMb; SSUM f[7.08M..7.47M); HL f[7.47M..13.77M)
  //  phase C: F1b bf16 (M*1536) = full region
  u16*   XMb   = (u16*)R1;
  u16*   DTb   = (u16*)R1;
  float* SSUM  = R1 + 7077888;             // 393,216 f
  float* HL    = R1 + 7471104;             // 6,291,456 f
  u16*   F1b   = (u16*)R1;
  u16*   Zb    = (u16*)(ws + 21233664);    // 14,155,776 u16 (= 7,077,888 f)
  float* DBC   = ws + 28311552;            // 1,032,192 f
  float* WB    = ws + 29343744;            // bf16 weights, 1,081,344 f slots
  u16*   inw_b   = (u16*)WB;                     // 589,824 sh
  u16*   xpw_pad = inw_b + 589824;               // 98,304 sh (128x768, rows 56+ zero)
  u16*   outw_b  = xpw_pad + 98304;              // 294,912 sh
  u16*   fc1w_b  = outw_b + 294912;              // 589,824 sh
  u16*   fc2w_b  = fc1w_b + 589824;              // 589,824 sh
  float* SCORES= ws + 30425088;            // 147,456 f
  float* WPOOL = ws + 30572544;            // 18,432
  float* MEANR = ws + 30590976;            // 18,432
  float* RSTDR = ws + 30609408;            // 18,432
  float* GC    = ws + 30627840;            // 3,072
  float* MODH  = ws + 30630912;            // 6,144
  float* MOD   = ws + 30637056;            // 3,072
  u16*   DT32b = (u16*)(ws + 30640128);    // 589,824 sh (M x 32 dt-input, K-pad)
  u16*   dtw_pad=(u16*)(ws + 30935040);    // 24,576 sh (768 x 32, cols 24+ zero)
  (void)ws_size; (void)n_in; (void)in_sizes; (void)out_size;

  // d_out as scratch: XN2b bf16 -> Ub bf16 -> Y bf16 (in-place over Ub) -> Hb bf16
  u16* XN2b = (u16*)d_out;
  u16* Ub   = (u16*)d_out;
  u16* Hb   = (u16*)d_out;

  // fused weight conversion + GC zero
  k_cvtall<<<(OEND+255)/256, 256, 0, stream>>>(inw, xpw, outw, fc1w, fc2w, dtw,
      inw_b, xpw_pad, outw_b, fc1w_b, fc2w_b, dtw_pad, GC);

  k_transpose<<<dim3(72,12,8), dim3(32,8), 0, stream>>>(x, XS);
  k_lnstats<<<MROWS, 64, 0, stream>>>(XS, n1g,n1b,n2g,n2b, apw,apb, MEANR, RSTDR, XN2b, SCORES);
  k_softmax_L<<<BB*NHD, 256, 0, stream>>>(SCORES);
  k_wpool<<<(MROWS+255)/256, 256, 0, stream>>>(SCORES, WPOOL);
  k_gc<<<dim3(BB,48), 384, 0, stream>>>(WPOOL, XS, MEANR, RSTDR, n1g, n1b, GC);
  k_mod1<<<dim3(BB,12), 64, 0, stream>>>(GC, modw1, modb1, MODH);
  k_mod2<<<dim3(BB,6), 64, 0, stream>>>(MODH, modw2, modb2, MOD);

  // in_proj fused: [XMb | Zb] = XN2 @ inw^T + inb   (K=384, N=1536, split store)
  k_mgemm<5><<<dim3(144,12), 256, 0, stream>>>(XN2b, inw_b, inb, XMb, 384, 1536, nullptr, Zb);
  // conv + silu -> Ub (bf16, in d_out; XN2b dead)
  k_conv<<<(MROWS*(DINN/8)+255)/256, 256, 0, stream>>>(XMb, convw, convb, Ub);
  // dbc = u @ xp_w^T (K=768): f32 DBC (col<56) + bf16 K-padded dt-input DT32b
  k_mgemm<6><<<dim3(144,1), 256, 0, stream>>>(Ub, xpw_pad, nullptr, DBC, 768, 56, nullptr, DT32b);
  // delta = softplus(DT32 @ dtw_pad^T + dtb) -> DTb bf16 (over dead XMb), K=32 MFMA
  k_mgemm<7><<<dim3(144,6), 256, 0, stream>>>(DT32b, dtw_pad, dtb, DTb, 32, 768, nullptr, nullptr);
  // chunked scan (d-per-thread, A-structure fast path)
  k_scan1<<<BB*NCH*3, 256, 0, stream>>>(DTb, Ub, DBC, Alog, SSUM, HL);
  k_scan2<<<384, 256, 0, stream>>>(SSUM, Alog, HL);
  k_scan3<<<BB*NCH*3, 256, 0, stream>>>(DTb, Ub, Zb, DBC, Alog, Dp, HL);
  // XS += (y @ out_w^T + out_b) * (1 + mod)   (K=768, N=384); Y lives in Ub slot
  k_mgemm<2><<<dim3(144,3), 256, 0, stream>>>(Ub, outw_b, outb, XS, 768, 384, MOD, nullptr);
  // Hb = LN3(XS)  (bf16, into d_out; Y dead)
  k_ln3<<<MROWS, 64, 0, stream>>>(XS, n3g, n3b, Hb);
  // F1b = gelu(H @ fc1_w^T + fc1_b)   (K=384, N=1536; overlays R1)
  k_mgemm<1><<<dim3(144,12), 256, 0, stream>>>(Hb, fc1w_b, fc1b, F1b, 384, 1536, nullptr, nullptr);
  // d_out = transpose(XS + F1 @ fc2_w^T + fc2_b)   (K=1536, N=384)
  k_mgemm<3><<<dim3(144,3), 256, 0, stream>>>(F1b, fc2w_b, fc2b, d_out, 1536, 384, XS, nullptr);
}

// Round 7
// 533.856 us; speedup vs baseline: 4.5221x; 1.0036x over previous
//
#include <hip/hip_runtime.h>
#include <math.h>

#define DIMC 384
#define NHD 8
#define NSTATE 16
#define DINN 768
#define DTRK 24
#define BB 8
#define LSEQ 2304
#define MROWS (BB*LSEQ)   // 18432
#define NCH 64
#define TCH 36            // LSEQ / NCH
#define L2E 1.44269504f

typedef unsigned short u16;
typedef short bf16x8 __attribute__((ext_vector_type(8)));
typedef float f32x4 __attribute__((ext_vector_type(4)));

__device__ __forceinline__ float sigmoid_(float x){ return 1.f/(1.f+__expf(-x)); }
__device__ __forceinline__ float silu_(float x){ return x*sigmoid_(x); }
__device__ __forceinline__ float softplus_(float x){ return (x>20.f)?x:log1pf(__expf(x)); }
__device__ __forceinline__ float gelu_(float x){
  float x3=x*x*x;
  return 0.5f*x*(1.f+tanhf(0.7978845608028654f*(x+0.044715f*x3)));
}
__device__ __forceinline__ float bfu2f(u16 u){
  union{unsigned int i; float f;} c; c.i=((unsigned int)u)<<16; return c.f;
}
__device__ __forceinline__ u16 f2bfu(float f){
  union{float f; unsigned int i;} c; c.f=f;
  unsigned int r = c.i + 0x7FFFu + ((c.i>>16)&1u);
  return (u16)(r>>16);
}
// async global->LDS, 16B per lane; dest must be wave-uniform base + lane*16
__device__ __forceinline__ void gl_lds16(const u16* g, u16* l){
  __builtin_amdgcn_global_load_lds((__attribute__((address_space(1))) void*)g,
      (__attribute__((address_space(3))) void*)l, 16, 0, 0);
}

// ---------------- fused weight convert + GC zero ----------------
#define O1 589824
#define O2 688128
#define O3 983040
#define O4 1572864
#define O5 2162688
#define O6 2187264
#define OEND 2190336
__global__ void k_cvtall(const float* __restrict__ inw, const float* __restrict__ xpw,
    const float* __restrict__ outw, const float* __restrict__ fc1w,
    const float* __restrict__ fc2w, const float* __restrict__ dtw,
    u16* __restrict__ inw_b, u16* __restrict__ xpw_pad, u16* __restrict__ outw_b,
    u16* __restrict__ fc1w_b, u16* __restrict__ fc2w_b, u16* __restrict__ dtw_pad,
    float* __restrict__ gc){
  int i = blockIdx.x*256+threadIdx.x;
  if(i >= OEND) return;
  if(i < O1){ inw_b[i]=f2bfu(inw[i]); }
  else if(i < O2){ int j=i-O1; xpw_pad[j] = (j<43008)? f2bfu(xpw[j]) : (u16)0; }
  else if(i < O3){ int j=i-O2; outw_b[j]=f2bfu(outw[j]); }
  else if(i < O4){ int j=i-O3; fc1w_b[j]=f2bfu(fc1w[j]); }
  else if(i < O5){ int j=i-O4; fc2w_b[j]=f2bfu(fc2w[j]); }
  else if(i < O6){ int j=i-O5; int r=j>>5, c=j&31;
                   dtw_pad[j] = (c<DTRK)? f2bfu(dtw[r*DTRK+c]) : (u16)0; }
  else { gc[i-O6]=0.f; }
}

// ---------------- transpose (B,C,L) -> (B,L,C) ----------------
__global__ void k_transpose(const float* __restrict__ x, float* __restrict__ xs){
  __shared__ float tile[32][33];
  int b = blockIdx.z;
  int t0 = blockIdx.x*32, c0 = blockIdx.y*32;
  int tx = threadIdx.x, ty = threadIdx.y; // 32 x 8
  const float* xb = x + (size_t)b*DIMC*LSEQ;
  #pragma unroll
  for(int q=0;q<4;q++)
    tile[ty+q*8][tx] = xb[(size_t)(c0+ty+q*8)*LSEQ + t0+tx];
  __syncthreads();
  float* xsb = xs + (size_t)b*LSEQ*DIMC;
  #pragma unroll
  for(int q=0;q<4;q++)
    xsb[(size_t)(t0+ty+q*8)*DIMC + c0+tx] = tile[tx][ty+q*8];
}

// -------- LN stats + LN2 (bf16 out) + attention scores --------
__global__ __launch_bounds__(64) void k_lnstats(const float* __restrict__ xs,
   const float* __restrict__ g1,const float* __restrict__ b1,
   const float* __restrict__ g2,const float* __restrict__ b2,
   const float* __restrict__ apw,const float* __restrict__ apb,
   float* __restrict__ meanr, float* __restrict__ rstdr,
   u16* __restrict__ xn2, float* __restrict__ scores){
  int row = blockIdx.x;
  int lane = threadIdx.x;
  const float* xr = xs + (size_t)row*DIMC;
  float v[6];
  float s=0.f, s2=0.f;
  #pragma unroll
  for(int i=0;i<6;i++){ v[i]=xr[lane+i*64]; s+=v[i]; s2+=v[i]*v[i]; }
  #pragma unroll
  for(int m=32;m>=1;m>>=1){ s += __shfl_xor(s,m); s2 += __shfl_xor(s2,m); }
  float mean = s*(1.f/DIMC);
  float var  = s2*(1.f/DIMC)-mean*mean;
  float rstd = rsqrtf(var+1e-5f);
  if(lane==0){ meanr[row]=mean; rstdr[row]=rstd; }
  float xv1[6];
  #pragma unroll
  for(int i=0;i<6;i++){
    int c = lane+i*64;
    float nx = (v[i]-mean)*rstd;
    xv1[i] = nx*g1[c]+b1[c];
    xn2[(size_t)row*DIMC+c] = f2bfu(nx*g2[c]+b2[c]);
  }
  #pragma unroll
  for(int h=0;h<NHD;h++){
    float p=0.f;
    #pragma unroll
    for(int i=0;i<6;i++) p += xv1[i]*apw[h*DIMC+lane+i*64];
    #pragma unroll
    for(int m=32;m>=1;m>>=1) p += __shfl_xor(p,m);
    if(lane==0) scores[(size_t)row*NHD+h]=p+apb[h];
  }
}

// ---------------- softmax over L per (b,h), in-place ----------------
__global__ __launch_bounds__(256) void k_softmax_L(float* __restrict__ sc){
  int bh = blockIdx.x; int b = bh>>3, h = bh&7;
  int tid = threadIdx.x;
  __shared__ float red[8];
  const size_t base = (size_t)b*LSEQ*NHD + h;
  float mx = -1e30f;
  for(int l=tid;l<LSEQ;l+=256) mx = fmaxf(mx, sc[base + (size_t)l*NHD]);
  #pragma unroll
  for(int m=32;m>=1;m>>=1) mx = fmaxf(mx, __shfl_xor(mx,m));
  if((tid&63)==0) red[tid>>6]=mx;
  __syncthreads();
  mx = fmaxf(fmaxf(red[0],red[1]),fmaxf(red[2],red[3]));
  float sum=0.f;
  for(int l=tid;l<LSEQ;l+=256) sum += __expf(sc[base+(size_t)l*NHD]-mx);
  #pragma unroll
  for(int m=32;m>=1;m>>=1) sum += __shfl_xor(sum,m);
  if((tid&63)==0) red[4+(tid>>6)]=sum;
  __syncthreads();
  float inv = 1.f/(red[4]+red[5]+red[6]+red[7]);
  for(int l=tid;l<LSEQ;l+=256){
    size_t idx = base+(size_t)l*NHD;
    sc[idx] = __expf(sc[idx]-mx)*inv;
  }
}

__global__ void k_wpool(const float* __restrict__ attn, float* __restrict__ w){
  int i = blockIdx.x*256+threadIdx.x;
  if(i<MROWS){
    const float* a = attn+(size_t)i*NHD;
    float s=0.f;
    #pragma unroll
    for(int h=0;h<NHD;h++) s+=a[h];
    w[i]=s*0.125f;
  }
}

// gc[b,c] = sum_l w[b,l]*xn1[b,l,c]  (xn1 recomputed from XS + mean/rstd)
__global__ __launch_bounds__(384) void k_gc(const float* __restrict__ w,
    const float* __restrict__ xs, const float* __restrict__ meanr,
    const float* __restrict__ rstdr, const float* __restrict__ g1,
    const float* __restrict__ b1, float* __restrict__ gc){
  int b = blockIdx.x; int chunk = blockIdx.y; int c = threadIdx.x;
  int l0 = chunk*48;
  float acc=0.f, accw=0.f;
  for(int l=0;l<48;l++){
    int row = b*LSEQ + l0+l;
    float ww = w[row];
    acc  += ww*(xs[(size_t)row*DIMC+c]-meanr[row])*rstdr[row];
    accw += ww;
  }
  atomicAdd(&gc[b*DIMC+c], acc*g1[c]+accw*b1[c]);
}

__global__ __launch_bounds__(64) void k_mod1(const float* __restrict__ gc,
    const float* __restrict__ w1, const float* __restrict__ b1, float* __restrict__ h){
  int b = blockIdx.x; int n = blockIdx.y*64+threadIdx.x;
  const float* g = gc + b*DIMC;
  const float* wr = w1 + (size_t)n*DIMC;
  float acc=0.f;
  for(int k=0;k<DIMC;k++) acc += g[k]*wr[k];
  h[b*768+n] = silu_(acc+b1[n]);
}
__global__ __launch_bounds__(64) void k_mod2(const float* __restrict__ h,
    const float* __restrict__ w2, const float* __restrict__ b2, float* __restrict__ mod){
  int b = blockIdx.x; int n = blockIdx.y*64+threadIdx.x;
  const float* hh = h + b*768;
  const float* wr = w2 + (size_t)n*768;
  float acc=0.f;
  for(int k=0;k<768;k++) acc += hh[k]*wr[k];
  mod[b*DIMC+n] = acc+b2[n];
}

// ======  bf16 MFMA GEMM: depth-2 prefetch, counted vmcnt, raw s_barrier  ======
// out = epi(A @ W^T + bias).  A:(M,K) bf16 row-major, W:(N,K) bf16 row-major.
// Tile 128x128, BK=32, 256 threads = 4 waves (2x2 of 64x64).
// Pipeline per K-step: vmcnt(4) [tile staged 2 iters ago] -> barrier ->
// ds_read -> lgkmcnt(0) -> barrier -> stage kb+64 into just-read buffer -> MFMA.
// Never drains vmcnt to 0 mid-loop (T3/T4 recipe).
template<int EPI>
__global__ __launch_bounds__(256,4) void k_mgemm(
    const u16* __restrict__ A, const u16* __restrict__ W,
    const float* __restrict__ bias, void* __restrict__ outp,
    int K, int N, const float* __restrict__ aux, void* __restrict__ outp2)
{
  __shared__ u16 lA[2][4096];   // [buf][kc:4][row:128][8]  (8 KB each)
  __shared__ u16 lB[2][4096];
  int tid = threadIdx.x;
  int m0 = blockIdx.x*128, n0 = blockIdx.y*128;
  int wid = tid>>6, lane = tid&63;
  int wr = wid>>1, wc = wid&1;
  int lrow = lane&15, lk = lane>>4;
  f32x4 acc[4][4];
  #pragma unroll
  for(int i=0;i<4;i++)
    #pragma unroll
    for(int j=0;j<4;j++){ acc[i][j][0]=0.f; acc[i][j][1]=0.f; acc[i][j][2]=0.f; acc[i][j][3]=0.f; }

  // staging map: flat = q*256 + tid; kc = flat>>7 (0..3), row = flat&127.
  int r0 = tid & 127, k0 = tid >> 7;
  const u16* Ag0 = A + (size_t)(m0+r0)*K + k0*8;
  const u16* Ag1 = A + (size_t)(m0+r0)*K + (k0+2)*8;
  const u16* Bg0 = W + (size_t)(n0+r0)*K + k0*8;
  const u16* Bg1 = W + (size_t)(n0+r0)*K + (k0+2)*8;

  // prologue: stage tiles 0 and 1 (8 loads/wave in flight)
  gl_lds16(Ag0, &lA[0][tid*8]);
  gl_lds16(Ag1, &lA[0][2048+tid*8]);
  gl_lds16(Bg0, &lB[0][tid*8]);
  gl_lds16(Bg1, &lB[0][2048+tid*8]);
  if(32 < K){
    gl_lds16(Ag0+32, &lA[1][tid*8]);
    gl_lds16(Ag1+32, &lA[1][2048+tid*8]);
    gl_lds16(Bg0+32, &lB[1][tid*8]);
    gl_lds16(Bg1+32, &lB[1][2048+tid*8]);
  }

  int cur = 0;
  for(int kb=0; kb<K; kb+=32){
    // wait for tile cur's 4 loads (oldest); next tile's 4 stay in flight
    if(kb+32 < K) asm volatile("s_waitcnt vmcnt(4)" ::: "memory");
    else          asm volatile("s_waitcnt vmcnt(0)" ::: "memory");
    __builtin_amdgcn_s_barrier();   // all waves' tile-cur writes visible
    bf16x8 af[4], bfr[4];
    #pragma unroll
    for(int i=0;i<4;i++){
      af[i]  = *reinterpret_cast<const bf16x8*>(&lA[cur][(lk*128 + wr*64 + i*16 + lrow)*8]);
      bfr[i] = *reinterpret_cast<const bf16x8*>(&lB[cur][(lk*128 + wc*64 + i*16 + lrow)*8]);
    }
    asm volatile("s_waitcnt lgkmcnt(0)" ::: "memory");  // my ds_reads done
    __builtin_amdgcn_s_barrier();                       // everyone's reads done
    if(kb+64 < K){   // stage tile kb+64 into the buffer just consumed
      gl_lds16(Ag0 + kb+64, &lA[cur][tid*8]);
      gl_lds16(Ag1 + kb+64, &lA[cur][2048+tid*8]);
      gl_lds16(Bg0 + kb+64, &lB[cur][tid*8]);
      gl_lds16(Bg1 + kb+64, &lB[cur][2048+tid*8]);
    }
    #pragma unroll
    for(int i=0;i<4;i++)
      #pragma unroll
      for(int j=0;j<4;j++)
        acc[i][j] = __builtin_amdgcn_mfma_f32_16x16x32_bf16(af[i], bfr[j], acc[i][j], 0,0,0);
    cur ^= 1;
  }

  #pragma unroll
  for(int i=0;i<4;i++){
    int row = m0 + wr*64 + i*16 + lk*4;
    #pragma unroll
    for(int j=0;j<4;j++){
      int col = n0 + wc*64 + j*16 + lrow;
      float bc = bias ? bias[col] : 0.f;
      f32x4 v = acc[i][j];
      if(EPI==0){
        u16* o = (u16*)outp;
        #pragma unroll
        for(int r=0;r<4;r++) o[(size_t)(row+r)*N + col] = f2bfu(v[r]+bc);
      } else if(EPI==1){
        u16* o = (u16*)outp;
        #pragma unroll
        for(int r=0;r<4;r++) o[(size_t)(row+r)*N + col] = f2bfu(gelu_(v[r]+bc));
      } else if(EPI==2){
        float* o = (float*)outp;
        int bi = row/LSEQ;
        float sc = 1.f + aux[bi*DIMC + col];
        #pragma unroll
        for(int r=0;r<4;r++) o[(size_t)(row+r)*DIMC + col] += (v[r]+bc)*sc;
      } else if(EPI==3){
        float* o = (float*)outp;
        int bi = row/LSEQ, t = row - bi*LSEQ;
        float4 s;
        s.x = aux[(size_t)(row+0)*DIMC+col] + v[0] + bc;
        s.y = aux[(size_t)(row+1)*DIMC+col] + v[1] + bc;
        s.z = aux[(size_t)(row+2)*DIMC+col] + v[2] + bc;
        s.w = aux[(size_t)(row+3)*DIMC+col] + v[3] + bc;
        *reinterpret_cast<float4*>(&o[((size_t)(bi*DIMC+col))*LSEQ + t]) = s;
      } else if(EPI==4){
        float* o = (float*)outp;
        if(col < N){
          #pragma unroll
          for(int r=0;r<4;r++) o[(size_t)(row+r)*N + col] = v[r]+bc;
        }
      } else if(EPI==5){ // split into two (M,768) bf16 outputs
        u16* o = (col < 768) ? (u16*)outp : (u16*)outp2;
        int cc = (col < 768) ? col : col - 768;
        #pragma unroll
        for(int r=0;r<4;r++) o[(size_t)(row+r)*768 + cc] = f2bfu(v[r]+bc);
      } else if(EPI==6){ // dbc f32 (col<56) + dt-input bf16 K-padded to 32
        float* o = (float*)outp;
        u16* o2 = (u16*)outp2;
        #pragma unroll
        for(int r=0;r<4;r++){
          float val = v[r];
          if(col < 56) o[(size_t)(row+r)*56 + col] = val;
          if(col < 32) o2[(size_t)(row+r)*32 + col] = (col<DTRK)? f2bfu(val) : (u16)0;
        }
      } else { // EPI==7: softplus -> bf16
        u16* o = (u16*)outp;
        #pragma unroll
        for(int r=0;r<4;r++) o[(size_t)(row+r)*N + col] = f2bfu(softplus_(v[r]+bc));
      }
    }
  }
}

// ------- causal depthwise conv K=4 + silu, 8 channels/thread (bf16 in/out) -------
__global__ void k_conv(const u16* __restrict__ xm, const float* __restrict__ cw,
                       const float* __restrict__ cb, u16* __restrict__ u){
  int idx = blockIdx.x*256+threadIdx.x;
  if(idx >= MROWS*(DINN/8)) return;
  int j = idx % (DINN/8); int r = idx / (DINN/8);
  int t = r % LSEQ; int d0 = j*8;
  float4 w4_[8];
  #pragma unroll
  for(int e=0;e<8;e++) w4_[e] = reinterpret_cast<const float4*>(cw)[d0+e];
  float acc[8];
  #pragma unroll
  for(int e=0;e<8;e++) acc[e]=cb[d0+e];
  #pragma unroll
  for(int k=0;k<4;k++){
    int tt=t+k-3;
    if(tt>=0){
      uint4 v = *reinterpret_cast<const uint4*>(&xm[(size_t)(r+k-3)*DINN + d0]);
      unsigned vv[4]={v.x,v.y,v.z,v.w};
      #pragma unroll
      for(int e=0;e<8;e++){
        u16 raw = (e&1)? (u16)(vv[e>>1]>>16) : (u16)(vv[e>>1]&0xffffu);
        float wk = (k==0)? w4_[e].x : (k==1)? w4_[e].y : (k==2)? w4_[e].z : w4_[e].w;
        acc[e] += bfu2f(raw)*wk;
      }
    }
  }
  u16 outv[8];
  #pragma unroll
  for(int e=0;e<8;e++) outv[e]=f2bfu(silu_(acc[e]));
  *reinterpret_cast<uint4*>(&u[(size_t)r*DINN+d0]) = *reinterpret_cast<const uint4*>(outv);
}

// ============ chunked selective scan, d-per-thread ============
__global__ __launch_bounds__(256) void k_scan1(
  const u16* __restrict__ dt_, const u16* __restrict__ u_,
  const float* __restrict__ dbc, const float* __restrict__ alog,
  float* __restrict__ ssum, float* __restrict__ hloc)
{
  __shared__ float Bsh[TCH][16];
  int bid = blockIdx.x;
  int b = bid/(NCH*3); int rem = bid%(NCH*3); int ch = rem/3; int dblk = rem%3;
  int tid = threadIdx.x; int d = dblk*256 + tid;
  size_t rbase = (size_t)b*LSEQ + (size_t)ch*TCH;
  for(int j=tid; j<TCH*16; j+=256){
    int row=j>>4, n=j&15;
    Bsh[row][n] = dbc[(rbase+row)*56 + DTRK + n];
  }
  float Acl2[16];
  float a0 = -__expf(alog[(size_t)d*16])*L2E;
  bool fast = true;
  #pragma unroll
  for(int n=0;n<16;n++){
    Acl2[n] = -__expf(alog[(size_t)d*16+n])*L2E;
    float tgt = (float)(n+1)*a0;
    fast = fast && (fabsf(Acl2[n]-tgt) <= 1e-4f*fabsf(tgt));
  }
  float h[16];
  #pragma unroll
  for(int n=0;n<16;n++) h[n]=0.f;
  float S=0.f;
  const u16* dtp = dt_ + rbase*DINN + d;
  const u16* up  = u_  + rbase*DINN + d;
  __syncthreads();
  if(fast){
    for(int t=0;t<TCH;t++){
      float dt = bfu2f(dtp[(size_t)t*DINN]);
      float uv = bfu2f(up[(size_t)t*DINN]);
      float G = dt*uv;
      S += dt;
      float e = exp2f(dt*a0), w = e;
      const float4* b4 = (const float4*)Bsh[t];
      float4 B0=b4[0],B1=b4[1],B2=b4[2],B3=b4[3];
      float Bv[16]={B0.x,B0.y,B0.z,B0.w,B1.x,B1.y,B1.z,B1.w,
                    B2.x,B2.y,B2.z,B2.w,B3.x,B3.y,B3.z,B3.w};
      #pragma unroll
      for(int n=0;n<16;n++){ h[n] = h[n]*w + G*Bv[n]; w *= e; }
    }
  } else {
    for(int t=0;t<TCH;t++){
      float dt = bfu2f(dtp[(size_t)t*DINN]);
      float uv = bfu2f(up[(size_t)t*DINN]);
      float G = dt*uv;
      S += dt;
      const float4* b4 = (const float4*)Bsh[t];
      float4 B0=b4[0],B1=b4[1],B2=b4[2],B3=b4[3];
      float Bv[16]={B0.x,B0.y,B0.z,B0.w,B1.x,B1.y,B1.z,B1.w,
                    B2.x,B2.y,B2.z,B2.w,B3.x,B3.y,B3.z,B3.w};
      #pragma unroll
      for(int n=0;n<16;n++) h[n] = h[n]*exp2f(dt*Acl2[n]) + G*Bv[n];
    }
  }
  ssum[((size_t)b*NCH+ch)*DINN + d] = S;
  float* hp = hloc + (((size_t)b*NCH+ch)*DINN + d)*16;
  #pragma unroll
  for(int n=0;n<16;n++) hp[n] = h[n];
}

__global__ __launch_bounds__(256) void k_scan2(
  const float* __restrict__ ssum, const float* __restrict__ alog,
  float* __restrict__ hl)
{
  int gid = blockIdx.x*256+threadIdx.x;   // B*DINN*16
  int n = gid & 15; int d = (gid>>4)%DINN; int b = gid/(DINN*NSTATE);
  float Acl2 = -__expf(alog[(size_t)d*16+n])*L2E;
  float hin=0.f;
  for(int ch=0; ch<NCH; ch++){
    size_t sidx = ((size_t)b*NCH+ch)*DINN + d;
    size_t idx  = sidx*16 + n;
    float a = exp2f(ssum[sidx]*Acl2);
    float hold = hl[idx];
    hl[idx] = hin;
    hin = a*hin + hold;
  }
}

__global__ __launch_bounds__(256) void k_scan3(
  const u16* __restrict__ dt_, u16* uy, const u16* __restrict__ z_,
  const float* __restrict__ dbc, const float* __restrict__ alog,
  const float* __restrict__ Dp, const float* __restrict__ hin)
{
  __shared__ float BC[TCH][32];
  int bid = blockIdx.x;
  int b = bid/(NCH*3); int rem = bid%(NCH*3); int ch = rem/3; int dblk = rem%3;
  int tid = threadIdx.x; int d = dblk*256 + tid;
  size_t rbase = (size_t)b*LSEQ + (size_t)ch*TCH;
  for(int j=tid; j<TCH*32; j+=256){
    int row=j>>5, c=j&31;
    BC[row][c] = dbc[(rbase+row)*56 + DTRK + c];
  }
  float Acl2[16], h[16];
  const float* hp = hin + (((size_t)b*NCH+ch)*DINN + d)*16;
  float a0 = -__expf(alog[(size_t)d*16])*L2E;
  bool fast = true;
  #pragma unroll
  for(int n=0;n<16;n++){
    Acl2[n] = -__expf(alog[(size_t)d*16+n])*L2E;
    float tgt = (float)(n+1)*a0;
    fast = fast && (fabsf(Acl2[n]-tgt) <= 1e-4f*fabsf(tgt));
    h[n] = hp[n];
  }
  float Dv = Dp[d];
  const u16* dtp = dt_ + rbase*DINN + d;
  u16*       uyp = uy  + rbase*DINN + d;
  const u16* zp  = z_  + rbase*DINN + d;
  __syncthreads();
  if(fast){
    for(int t=0;t<TCH;t++){
      float dt = bfu2f(dtp[(size_t)t*DINN]);
      float uv = bfu2f(uyp[(size_t)t*DINN]);
      float zv = bfu2f(zp[(size_t)t*DINN]);
      float G = dt*uv;
      float e = exp2f(dt*a0), w = e;
      const float4* bc4 = (const float4*)BC[t];
      float4 B0=bc4[0],B1=bc4[1],B2=bc4[2],B3=bc4[3];
      float4 C0=bc4[4],C1=bc4[5],C2=bc4[6],C3=bc4[7];
      float Bv[16]={B0.x,B0.y,B0.z,B0.w,B1.x,B1.y,B1.z,B1.w,
                    B2.x,B2.y,B2.z,B2.w,B3.x,B3.y,B3.z,B3.w};
      float Cv[16]={C0.x,C0.y,C0.z,C0.w,C1.x,C1.y,C1.z,C1.w,
                    C2.x,C2.y,C2.z,C2.w,C3.x,C3.y,C3.z,C3.w};
      float y0=0.f,y1=0.f,y2=0.f,y3=0.f;
      #pragma unroll
      for(int n=0;n<16;n++){
        h[n] = h[n]*w + G*Bv[n];
        w *= e;
        if((n&3)==0) y0 += h[n]*Cv[n];
        else if((n&3)==1) y1 += h[n]*Cv[n];
        else if((n&3)==2) y2 += h[n]*Cv[n];
        else y3 += h[n]*Cv[n];
      }
      float y = (y0+y1)+(y2+y3);
      uyp[(size_t)t*DINN] = f2bfu((y + uv*Dv)*silu_(zv));
    }
  } else {
    for(int t=0;t<TCH;t++){
      float dt = bfu2f(dtp[(size_t)t*DINN]);
      float uv = bfu2f(uyp[(size_t)t*DINN]);
      float zv = bfu2f(zp[(size_t)t*DINN]);
      float G = dt*uv;
      const float4* bc4 = (const float4*)BC[t];
      float4 B0=bc4[0],B1=bc4[1],B2=bc4[2],B3=bc4[3];
      float4 C0=bc4[4],C1=bc4[5],C2=bc4[6],C3=bc4[7];
      float Bv[16]={B0.x,B0.y,B0.z,B0.w,B1.x,B1.y,B1.z,B1.w,
                    B2.x,B2.y,B2.z,B2.w,B3.x,B3.y,B3.z,B3.w};
      float Cv[16]={C0.x,C0.y,C0.z,C0.w,C1.x,C1.y,C1.z,C1.w,
                    C2.x,C2.y,C2.z,C2.w,C3.x,C3.y,C3.z,C3.w};
      float y0=0.f,y1=0.f,y2=0.f,y3=0.f;
      #pragma unroll
      for(int n=0;n<16;n++){
        h[n] = h[n]*exp2f(dt*Acl2[n]) + G*Bv[n];
        if((n&3)==0) y0 += h[n]*Cv[n];
        else if((n&3)==1) y1 += h[n]*Cv[n];
        else if((n&3)==2) y2 += h[n]*Cv[n];
        else y3 += h[n]*Cv[n];
      }
      float y = (y0+y1)+(y2+y3);
      uyp[(size_t)t*DINN] = f2bfu((y + uv*Dv)*silu_(zv));
    }
  }
}

// ---------------- LN3, bf16 out ----------------
__global__ __launch_bounds__(64) void k_ln3(const float* __restrict__ xin,
    const float* __restrict__ g, const float* __restrict__ bb, u16* __restrict__ xout){
  int row = blockIdx.x;
  int lane = threadIdx.x;
  const float* xr = xin + (size_t)row*DIMC;
  float v[6];
  float s=0.f, s2=0.f;
  #pragma unroll
  for(int i=0;i<6;i++){ v[i]=xr[lane+i*64]; s+=v[i]; s2+=v[i]*v[i]; }
  #pragma unroll
  for(int m=32;m>=1;m>>=1){ s += __shfl_xor(s,m); s2 += __shfl_xor(s2,m); }
  float mean = s*(1.f/DIMC);
  float var  = s2*(1.f/DIMC)-mean*mean;
  float rstd = rsqrtf(var+1e-5f);
  #pragma unroll
  for(int i=0;i<6;i++){
    int c = lane+i*64;
    xout[(size_t)row*DIMC+c] = f2bfu((v[i]-mean)*rstd*g[c]+bb[c]);
  }
}

extern "C" void kernel_launch(void* const* d_in, const int* in_sizes, int n_in,
                              void* d_out, int out_size, void* d_ws, size_t ws_size,
                              hipStream_t stream)
{
  const float* x     = (const float*)d_in[0];
  const float* n1g   = (const float*)d_in[1];
  const float* n1b   = (const float*)d_in[2];
  const float* apw   = (const float*)d_in[3];
  const float* apb   = (const float*)d_in[4];
  const float* n2g   = (const float*)d_in[5];
  const float* n2b   = (const float*)d_in[6];
  const float* inw   = (const float*)d_in[7];
  const float* inb   = (const float*)d_in[8];
  const float* convw = (const float*)d_in[9];
  const float* convb = (const float*)d_in[10];
  const float* xpw   = (const float*)d_in[11];
  const float* dtw   = (const float*)d_in[12];
  const float* dtb   = (const float*)d_in[13];
  const float* Alog  = (const float*)d_in[14];
  const float* Dp    = (const float*)d_in[15];
  const float* outw  = (const float*)d_in[16];
  const float* outb  = (const float*)d_in[17];
  const float* modw1 = (const float*)d_in[18];
  const float* modb1 = (const float*)d_in[19];
  const float* modw2 = (const float*)d_in[20];
  const float* modb2 = (const float*)d_in[21];
  const float* n3g   = (const float*)d_in[22];
  const float* n3b   = (const float*)d_in[23];
  const float* fc1w  = (const float*)d_in[24];
  const float* fc1b  = (const float*)d_in[25];
  const float* fc2w  = (const float*)d_in[26];
  const float* fc2b  = (const float*)d_in[27];

  // ---- workspace layout (f32 slots), total ~30.95M f = 123.8 MB ----
  float* ws = (float*)d_ws;
  float* XS    = ws;                       // 7,077,888 f
  float* R1    = ws + 7077888;             // 14,155,776 f multi-use region
  u16*   XMb   = (u16*)R1;
  u16*   DTb   = (u16*)R1;
  float* SSUM  = R1 + 7077888;             // 393,216 f
  float* HL    = R1 + 7471104;             // 6,291,456 f
  u16*   F1b   = (u16*)R1;
  u16*   Zb    = (u16*)(ws + 21233664);    // 14,155,776 u16 (= 7,077,888 f)
  float* DBC   = ws + 28311552;            // 1,032,192 f
  float* WB    = ws + 29343744;            // bf16 weights, 1,081,344 f slots
  u16*   inw_b   = (u16*)WB;                     // 589,824 sh
  u16*   xpw_pad = inw_b + 589824;               // 98,304 sh (128x768, rows 56+ zero)
  u16*   outw_b  = xpw_pad + 98304;              // 294,912 sh
  u16*   fc1w_b  = outw_b + 294912;              // 589,824 sh
  u16*   fc2w_b  = fc1w_b + 589824;              // 589,824 sh
  float* SCORES= ws + 30425088;            // 147,456 f
  float* WPOOL = ws + 30572544;            // 18,432
  float* MEANR = ws + 30590976;            // 18,432
  float* RSTDR = ws + 30609408;            // 18,432
  float* GC    = ws + 30627840;            // 3,072
  float* MODH  = ws + 30630912;            // 6,144
  float* MOD   = ws + 30637056;            // 3,072
  u16*   DT32b = (u16*)(ws + 30640128);    // 589,824 sh (M x 32 dt-input, K-pad)
  u16*   dtw_pad=(u16*)(ws + 30935040);    // 24,576 sh (768 x 32, cols 24+ zero)
  (void)ws_size; (void)n_in; (void)in_sizes; (void)out_size;

  // d_out as scratch: XN2b bf16 -> Ub bf16 -> Y bf16 (in-place over Ub) -> Hb bf16
  u16* XN2b = (u16*)d_out;
  u16* Ub   = (u16*)d_out;
  u16* Hb   = (u16*)d_out;

  // fused weight conversion + GC zero
  k_cvtall<<<(OEND+255)/256, 256, 0, stream>>>(inw, xpw, outw, fc1w, fc2w, dtw,
      inw_b, xpw_pad, outw_b, fc1w_b, fc2w_b, dtw_pad, GC);

  k_transpose<<<dim3(72,12,8), dim3(32,8), 0, stream>>>(x, XS);
  k_lnstats<<<MROWS, 64, 0, stream>>>(XS, n1g,n1b,n2g,n2b, apw,apb, MEANR, RSTDR, XN2b, SCORES);
  k_softmax_L<<<BB*NHD, 256, 0, stream>>>(SCORES);
  k_wpool<<<(MROWS+255)/256, 256, 0, stream>>>(SCORES, WPOOL);
  k_gc<<<dim3(BB,48), 384, 0, stream>>>(WPOOL, XS, MEANR, RSTDR, n1g, n1b, GC);
  k_mod1<<<dim3(BB,12), 64, 0, stream>>>(GC, modw1, modb1, MODH);
  k_mod2<<<dim3(BB,6), 64, 0, stream>>>(MODH, modw2, modb2, MOD);

  // in_proj fused: [XMb | Zb] = XN2 @ inw^T + inb   (K=384, N=1536, split store)
  k_mgemm<5><<<dim3(144,12), 256, 0, stream>>>(XN2b, inw_b, inb, XMb, 384, 1536, nullptr, Zb);
  // conv + silu -> Ub (bf16, in d_out; XN2b dead)
  k_conv<<<(MROWS*(DINN/8)+255)/256, 256, 0, stream>>>(XMb, convw, convb, Ub);
  // dbc = u @ xp_w^T (K=768): f32 DBC (col<56) + bf16 K-padded dt-input DT32b
  k_mgemm<6><<<dim3(144,1), 256, 0, stream>>>(Ub, xpw_pad, nullptr, DBC, 768, 56, nullptr, DT32b);
  // delta = softplus(DT32 @ dtw_pad^T + dtb) -> DTb bf16 (over dead XMb), K=32 MFMA
  k_mgemm<7><<<dim3(144,6), 256, 0, stream>>>(DT32b, dtw_pad, dtb, DTb, 32, 768, nullptr, nullptr);
  // chunked scan (d-per-thread, A-structure fast path)
  k_scan1<<<BB*NCH*3, 256, 0, stream>>>(DTb, Ub, DBC, Alog, SSUM, HL);
  k_scan2<<<384, 256, 0, stream>>>(SSUM, Alog, HL);
  k_scan3<<<BB*NCH*3, 256, 0, stream>>>(DTb, Ub, Zb, DBC, Alog, Dp, HL);
  // XS += (y @ out_w^T + out_b) * (1 + mod)   (K=768, N=384); Y lives in Ub slot
  k_mgemm<2><<<dim3(144,3), 256, 0, stream>>>(Ub, outw_b, outb, XS, 768, 384, MOD, nullptr);
  // Hb = LN3(XS)  (bf16, into d_out; Y dead)
  k_ln3<<<MROWS, 64, 0, stream>>>(XS, n3g, n3b, Hb);
  // F1b = gelu(H @ fc1_w^T + fc1_b)   (K=384, N=1536; overlays R1)
  k_mgemm<1><<<dim3(144,12), 256, 0, stream>>>(Hb, fc1w_b, fc1b, F1b, 384, 1536, nullptr, nullptr);
  // d_out = transpose(XS + F1 @ fc2_w^T + fc2_b)   (K=1536, N=384)
  k_mgemm<3><<<dim3(144,3), 256, 0, stream>>>(F1b, fc2w_b, fc2b, d_out, 1536, 384, XS, nullptr);
}